// Round 6
// baseline (2704.560 us; speedup 1.0000x reference)
//
#include <hip/hip_runtime.h>
#include <cstddef>
#include <cstdint>

#define TOK    49      // tokens (7x7)
#define NH     8       // heads
#define DHEAD  128     // v head dim
#define HQKV   1536    // qkv channels
#define DHTOT  1024    // NH*DHEAD
#define DIMM   384     // model dim

typedef unsigned short u16;
typedef float  f32x4  __attribute__((ext_vector_type(4)));
typedef __bf16 bf16x8 __attribute__((ext_vector_type(8)));

typedef const __attribute__((address_space(1))) void gas_void;
typedef __attribute__((address_space(3))) void las_void;

static __device__ __forceinline__ u16 f2bf(float f) {
    unsigned int u = __builtin_bit_cast(unsigned int, f);
    return (u16)((u + 0x7fffu + ((u >> 16) & 1u)) >> 16);   // RNE
}

// XOR swizzle for [*][64]-short images: 8-short (16B) slots, slot ^= row&7.
static __device__ __forceinline__ int swz64(int row, int c) {
    return (row << 6) + ((((c >> 3) ^ (row & 7)) << 3) | (c & 7));
}
// Same swizzle for the [64][384] A image.
static __device__ __forceinline__ int swzA(int row, int c) {
    return row * 384 + ((((c >> 3) ^ (row & 7)) << 3) | (c & 7));
}

// ---------------------------------------------------------------------------
// qkv_w [1536][384] fp32 -> bf16 head-tiles, pre-swizzled for global_load_lds:
// out[((h*6 + t)*192 + r)*64 + ((cb ^ (r&7))*8 + c)] = W[h*192+r][t*64 + cb*8 + c]
// ---------------------------------------------------------------------------
__global__ __launch_bounds__(256)
void cast_swz_wq(const float* __restrict__ in, u16* __restrict__ out)
{
    int i = blockIdx.x * 256 + threadIdx.x;          // slot index
    if (i >= (HQKV * DIMM) / 8) return;
    int R   = i / 48, rem = i - R * 48;
    int t   = rem >> 3, cb = rem & 7;
    int h   = R / 192, r = R - h * 192;
    const float* src = in + (size_t)R * DIMM + t * 64 + cb * 8;
    float4 a0 = *reinterpret_cast<const float4*>(src);
    float4 a1 = *reinterpret_cast<const float4*>(src + 4);
    uint4 o;
    o.x = f2bf(a0.x) | ((unsigned)f2bf(a0.y) << 16);
    o.y = f2bf(a0.z) | ((unsigned)f2bf(a0.w) << 16);
    o.z = f2bf(a1.x) | ((unsigned)f2bf(a1.y) << 16);
    o.w = f2bf(a1.z) | ((unsigned)f2bf(a1.w) << 16);
    int slot = cb ^ (r & 7);
    *reinterpret_cast<uint4*>(out + ((size_t)(h * 6 + t) * 192 + r) * 64 + slot * 8) = o;
}

// ---------------------------------------------------------------------------
// plain fp32 -> bf16 cast (proj weights)
// ---------------------------------------------------------------------------
__global__ __launch_bounds__(256)
void cast_f32_to_bf16(const float* __restrict__ in, u16* __restrict__ out, long n8)
{
    long i = (long)blockIdx.x * 256 + threadIdx.x;
    const long stride = (long)gridDim.x * 256;
    for (; i < n8; i += stride) {
        float4 v0 = reinterpret_cast<const float4*>(in)[i * 2];
        float4 v1 = reinterpret_cast<const float4*>(in)[i * 2 + 1];
        uint4 o;
        o.x = f2bf(v0.x) | ((unsigned)f2bf(v0.y) << 16);
        o.y = f2bf(v0.z) | ((unsigned)f2bf(v0.w) << 16);
        o.z = f2bf(v1.x) | ((unsigned)f2bf(v1.y) << 16);
        o.w = f2bf(v1.z) | ((unsigned)f2bf(v1.w) << 16);
        reinterpret_cast<uint4*>(out)[i] = o;
    }
}

// ---------------------------------------------------------------------------
// bias_full[h][n*49+m] = attn_bias[h][bias_idxs[n*49+m]]
// ---------------------------------------------------------------------------
__global__ __launch_bounds__(256)
void bias_expand(const float* __restrict__ attn_bias, const int* __restrict__ idxs,
                 float* __restrict__ bias_full, int n_off)
{
    int i = blockIdx.x * 256 + threadIdx.x;
    if (i < NH * TOK * TOK) {
        int h = i / (TOK * TOK), s = i - h * (TOK * TOK);
        bias_full[i] = attn_bias[h * n_off + idxs[s]];
    }
}

// ---------------------------------------------------------------------------
// Fused cast + QKV GEMM + attention. One block per batch, 512 threads/8 waves.
// LDS: As[64][384] bf16 swz (x, pad rows 0), Wt[2][192*64] dbuf (S/Ps overlay),
//      QKs[64][64] (q|k), Vts[128][64] (V^T: row=d, col=token).
// ---------------------------------------------------------------------------
__global__ __launch_bounds__(512)
void fused_qkv_attn(const float* __restrict__ x,        // [B*49][384] fp32
                    const u16*   __restrict__ wq,       // swizzled head-tiles
                    const float* __restrict__ qkv_b,    // [1536]
                    const float* __restrict__ bias_full,// [NH][49*49]
                    u16*         __restrict__ ab)       // [B*49][1024] bf16
{
    __shared__ __align__(16) u16 As[64 * 384];     // 49152 B
    __shared__ __align__(16) u16 Wt[2][12288];     // 49152 B (phase-shared)
    __shared__ __align__(16) u16 QKs[64 * 64];     // 8192 B
    __shared__ __align__(16) u16 Vts[128 * 64];    // 16384 B

    float* Sb = (float*)&Wt[0][0];                 // [64][80] f32 = 20480 B
    u16*   Ps = &Wt[1][0];                         // [64*64] bf16 = 8192 B

    const int tid  = threadIdx.x;
    const int lane = tid & 63;
    const int w    = tid >> 6;          // wave 0..7
    const int fr   = lane & 15;
    const int fg   = lane >> 4;         // 0..3
    const int b    = blockIdx.x;

    const int tf  = w >> 1;             // token-frag (qk GEMM rows, attn rows)
    const int cf0 = (w & 1) * 2;        // qk channel-frag base / S col base
    const int dj0 = (w & 1) * 4;        // PV d-frag base

    // ---- stage x -> As (bf16, swizzled); rows >= TOK zeroed ----
    for (int idx = tid; idx < 64 * 48; idx += 512) {
        const int row = idx / 48, c8 = idx - row * 48;
        uint4 o = make_uint4(0, 0, 0, 0);
        if (row < TOK) {
            const float* src = x + ((size_t)b * TOK + row) * DIMM + c8 * 8;
            float4 a0 = *reinterpret_cast<const float4*>(src);
            float4 a1 = *reinterpret_cast<const float4*>(src + 4);
            o.x = f2bf(a0.x) | ((unsigned)f2bf(a0.y) << 16);
            o.y = f2bf(a0.z) | ((unsigned)f2bf(a0.w) << 16);
            o.z = f2bf(a1.x) | ((unsigned)f2bf(a1.y) << 16);
            o.w = f2bf(a1.z) | ((unsigned)f2bf(a1.w) << 16);
        }
        *reinterpret_cast<uint4*>(&As[swzA(row, c8 * 8)]) = o;
    }

    const float scale = 0.17677669529663687f;      // 32^-0.5

    for (int h = 0; h < NH; ++h) {
        const u16* wh = wq + (size_t)h * 6 * 12288;

        // prefetch k-step 0 into buf 0 (prev head's attn done: barrier at end)
        #pragma unroll
        for (int i = 0; i < 3; ++i)
            __builtin_amdgcn_global_load_lds((gas_void*)(wh + (i * 512 + tid) * 8),
                                             (las_void*)(&Wt[0][(i * 512 + w * 64) * 8]), 16, 0, 0);

        f32x4 aqk[2]; f32x4 av[4];
        #pragma unroll
        for (int c = 0; c < 2; ++c) aqk[c] = (f32x4)0.0f;
        #pragma unroll
        for (int n = 0; n < 4; ++n) av[n] = (f32x4)0.0f;

        for (int t = 0; t < 6; ++t) {
            __syncthreads();                        // buf[t&1] staged (vmcnt drained)
            if (t < 5) {                            // prefetch next, flies during compute
                const u16* g = wh + (t + 1) * 12288;
                #pragma unroll
                for (int i = 0; i < 3; ++i)
                    __builtin_amdgcn_global_load_lds((gas_void*)(g + (i * 512 + tid) * 8),
                                                     (las_void*)(&Wt[(t + 1) & 1][(i * 512 + w * 64) * 8]), 16, 0, 0);
            }
            const u16* W0 = Wt[t & 1];
            #pragma unroll
            for (int ks = 0; ks < 2; ++ks) {
                const int kk = t * 64 + ks * 32 + fg * 8;   // col in As
                const int kw = ks * 32 + fg * 8;            // col in Wt
                bf16x8 af[4];
                #pragma unroll
                for (int n = 0; n < 4; ++n)
                    af[n] = *reinterpret_cast<const bf16x8*>(&As[swzA(16 * n + fr, kk)]);
                #pragma unroll
                for (int c = 0; c < 2; ++c) {
                    bf16x8 wf = *reinterpret_cast<const bf16x8*>(&W0[swz64(16 * (cf0 + c) + fr, kw)]);
                    aqk[c] = __builtin_amdgcn_mfma_f32_16x16x32_bf16(af[tf], wf, aqk[c], 0, 0, 0);
                }
                bf16x8 wv = *reinterpret_cast<const bf16x8*>(&W0[swz64(64 + 16 * w + fr, kw)]);
                #pragma unroll
                for (int n = 0; n < 4; ++n)
                    av[n] = __builtin_amdgcn_mfma_f32_16x16x32_bf16(wv, af[n], av[n], 0, 0, 0);
            }
        }

        // ---- epilogue: +bias, cvt, scatter to QKs / Vts (swizzled, 2-way max) ----
        // qk: D col = channel = 16*(cf0+c)+fr ; D row = token = 16*tf + fg*4 + j
        #pragma unroll
        for (int c = 0; c < 2; ++c) {
            const float bq = qkv_b[h * 192 + 16 * (cf0 + c) + fr];
            #pragma unroll
            for (int j = 0; j < 4; ++j)
                QKs[swz64(16 * tf + fg * 4 + j, 16 * (cf0 + c) + fr)] = f2bf(aqk[c][j] + bq);
        }
        // v (operand-swapped): D col = token = 16*n+fr ; D row = d = 16*w + fg*4 + j
        #pragma unroll
        for (int j = 0; j < 4; ++j) {
            const float bv = qkv_b[h * 192 + 64 + 16 * w + fg * 4 + j];
            #pragma unroll
            for (int n = 0; n < 4; ++n)
                Vts[swz64(16 * w + fg * 4 + j, 16 * n + fr)] = f2bf(av[n][j] + bv);
        }
        __syncthreads();   // QKs/Vts visible; Wt region free -> becomes S/Ps

        // ---- QK^T: S rows 16tf.., cols 16(cf0+c).. ----
        {
            bf16x8 qf = *reinterpret_cast<const bf16x8*>(&QKs[swz64(16 * tf + fr, fg * 8)]);
            f32x4 sacc[2];
            #pragma unroll
            for (int c = 0; c < 2; ++c) {
                bf16x8 kf = *reinterpret_cast<const bf16x8*>(&QKs[swz64(16 * (cf0 + c) + fr, 32 + fg * 8)]);
                sacc[c] = __builtin_amdgcn_mfma_f32_16x16x32_bf16(qf, kf, (f32x4)0.0f, 0, 0, 0);
            }
            const float* bh_bias = bias_full + h * (TOK * TOK);
            #pragma unroll
            for (int c = 0; c < 2; ++c) {
                #pragma unroll
                for (int j = 0; j < 4; ++j) {
                    const int row = 16 * tf + fg * 4 + j;
                    const int col = 16 * (cf0 + c) + fr;
                    const int rn = row < TOK ? row : TOK - 1;
                    const int cm = col < TOK ? col : TOK - 1;
                    Sb[row * 80 + col] = sacc[c][j] * scale + bh_bias[rn * TOK + cm];
                }
            }
        }
        __syncthreads();

        // ---- softmax: 8 threads per row; thread j owns cols 8j..8j+7 ----
        {
            const int n = tid >> 3, j = tid & 7;
            const float* Sr = Sb + n * 80 + j * 8;
            float4 s0 = *reinterpret_cast<const float4*>(Sr);
            float4 s1 = *reinterpret_cast<const float4*>(Sr + 4);
            float v[8] = {s0.x, s0.y, s0.z, s0.w, s1.x, s1.y, s1.z, s1.w};
            float mx = -1e30f;
            #pragma unroll
            for (int e = 0; e < 8; ++e)
                if (j * 8 + e < TOK) mx = fmaxf(mx, v[e]);
            mx = fmaxf(mx, __shfl_xor(mx, 1, 8));
            mx = fmaxf(mx, __shfl_xor(mx, 2, 8));
            mx = fmaxf(mx, __shfl_xor(mx, 4, 8));
            float sum = 0.f;
            #pragma unroll
            for (int e = 0; e < 8; ++e) {
                const float ev = (j * 8 + e < TOK) ? __expf(v[e] - mx) : 0.f;
                v[e] = ev; sum += ev;
            }
            sum += __shfl_xor(sum, 1, 8);
            sum += __shfl_xor(sum, 2, 8);
            sum += __shfl_xor(sum, 4, 8);
            const float inv = 1.f / sum;
            uint4 o;
            o.x = f2bf(v[0] * inv) | ((unsigned)f2bf(v[1] * inv) << 16);
            o.y = f2bf(v[2] * inv) | ((unsigned)f2bf(v[3] * inv) << 16);
            o.z = f2bf(v[4] * inv) | ((unsigned)f2bf(v[5] * inv) << 16);
            o.w = f2bf(v[6] * inv) | ((unsigned)f2bf(v[7] * inv) << 16);
            *reinterpret_cast<uint4*>(&Ps[swz64(n, j * 8)]) = o;
        }
        __syncthreads();

        // ---- PV: O rows 16tf.., d cols 16(dj0+c).. ----
        {
            f32x4 oacc[4];
            #pragma unroll
            for (int c = 0; c < 4; ++c) oacc[c] = (f32x4)0.0f;
            #pragma unroll
            for (int ks = 0; ks < 2; ++ks) {
                bf16x8 pf = *reinterpret_cast<const bf16x8*>(&Ps[swz64(16 * tf + fr, ks * 32 + fg * 8)]);
                #pragma unroll
                for (int c = 0; c < 4; ++c) {
                    bf16x8 vf = *reinterpret_cast<const bf16x8*>(&Vts[swz64(16 * (dj0 + c) + fr, ks * 32 + fg * 8)]);
                    oacc[c] = __builtin_amdgcn_mfma_f32_16x16x32_bf16(pf, vf, oacc[c], 0, 0, 0);
                }
            }
            u16* ob = ab + (size_t)b * TOK * DHTOT + h * DHEAD;
            #pragma unroll
            for (int c = 0; c < 4; ++c) {
                #pragma unroll
                for (int j = 0; j < 4; ++j) {
                    const int n = 16 * tf + fg * 4 + j;
                    if (n < TOK)
                        ob[(size_t)n * DHTOT + 16 * (dj0 + c) + fr] = f2bf(oacc[c][j]);
                }
            }
        }
        __syncthreads();   // Ps/Vts reads done -> next head may restage Wt/QKs/Vts
    }
}

// ---------------------------------------------------------------------------
// Proj GEMM (validated r5): C[M,384] = A[M,1024] @ W[384,1024]^T + bias, fp32.
// ---------------------------------------------------------------------------
__global__ __launch_bounds__(256)
void gemm_bf16_nt(const u16* __restrict__ A, const u16* __restrict__ W,
                  const float* __restrict__ bias, float* __restrict__ C,
                  int M, int N, int K)
{
    __shared__ u16 Alds[128 * 64];
    __shared__ u16 Blds[128 * 64];

    const int t    = threadIdx.x;
    const int lane = t & 63;
    const int wv   = t >> 6;
    const int wr   = wv >> 1;
    const int wc   = wv & 1;
    const int bm   = blockIdx.x * 128;
    const int bn   = blockIdx.y * 128;

    const int lrow = lane >> 3;
    const int lcol = (lane & 7) * 8;
    const int frow = lane & 15;
    const int fk   = (lane >> 4) * 8;

    f32x4 acc[4][4];
    #pragma unroll
    for (int mi = 0; mi < 4; ++mi)
        #pragma unroll
        for (int ni = 0; ni < 4; ++ni) acc[mi][ni] = (f32x4)0.0f;

    for (int k0 = 0; k0 < K; k0 += 64) {
        #pragma unroll
        for (int i = 0; i < 4; ++i) {
            const int c   = i * 4 + wv;
            const int row = c * 8 + lrow;
            __builtin_amdgcn_global_load_lds((gas_void*)(A + (size_t)(bm + row) * K + k0 + lcol),
                                             (las_void*)(Alds + c * 512), 16, 0, 0);
            __builtin_amdgcn_global_load_lds((gas_void*)(W + (size_t)(bn + row) * K + k0 + lcol),
                                             (las_void*)(Blds + c * 512), 16, 0, 0);
        }
        __syncthreads();
        #pragma unroll
        for (int ks = 0; ks < 64; ks += 32) {
            bf16x8 af[4], bf[4];
            #pragma unroll
            for (int mi = 0; mi < 4; ++mi)
                af[mi] = *reinterpret_cast<const bf16x8*>(&Alds[(wr * 64 + mi * 16 + frow) * 64 + ks + fk]);
            #pragma unroll
            for (int ni = 0; ni < 4; ++ni)
                bf[ni] = *reinterpret_cast<const bf16x8*>(&Blds[(wc * 64 + ni * 16 + frow) * 64 + ks + fk]);
            #pragma unroll
            for (int mi = 0; mi < 4; ++mi)
                #pragma unroll
                for (int ni = 0; ni < 4; ++ni)
                    acc[mi][ni] = __builtin_amdgcn_mfma_f32_16x16x32_bf16(af[mi], bf[ni], acc[mi][ni], 0, 0, 0);
        }
        __syncthreads();
    }

    const int rbase = (lane >> 4) * 4;
    #pragma unroll
    for (int ni = 0; ni < 4; ++ni) {
        const int col = bn + wc * 64 + ni * 16 + frow;
        const float bv = bias[col];
        #pragma unroll
        for (int mi = 0; mi < 4; ++mi) {
            #pragma unroll
            for (int j = 0; j < 4; ++j) {
                const int row = bm + wr * 64 + mi * 16 + rbase + j;
                C[(size_t)row * N + col] = acc[mi][ni][j] + bv;
            }
        }
    }
}

// ---------------------------------------------------------------------------
extern "C" void kernel_launch(void* const* d_in, const int* in_sizes, int n_in,
                              void* d_out, int out_size, void* d_ws, size_t ws_size,
                              hipStream_t stream)
{
    const float* x         = (const float*)d_in[0];
    const float* qkv_w     = (const float*)d_in[1];
    const float* qkv_b     = (const float*)d_in[2];
    const float* proj_w    = (const float*)d_in[3];
    const float* proj_b    = (const float*)d_in[4];
    const float* attn_bias = (const float*)d_in[5];
    const int*   bias_idxs = (const int*)d_in[6];

    const int Mtot  = in_sizes[0] / DIMM;            // 100352
    const int Btot  = Mtot / TOK;                    // 2048
    const int n_off = in_sizes[5] / NH;              // 49

    // workspace layout (all 16B aligned)
    const size_t ab_bytes = (size_t)Mtot * DHTOT * 2;          // 205,520,896
    const size_t bf_bytes = (size_t)NH * TOK * TOK * 4;        // 76,832
    const size_t wq_bytes = (size_t)HQKV * DIMM * 2;           // 1,179,648
    const size_t wp_bytes = (size_t)DIMM * DHTOT * 2;          // 786,432
    if (ws_size < ab_bytes + bf_bytes + wq_bytes + wp_bytes) return;

    u16*   ab        = (u16*)d_ws;
    float* bias_full = (float*)((char*)d_ws + ab_bytes);
    u16*   wq        = (u16*)((char*)d_ws + ab_bytes + bf_bytes);
    u16*   wp        = (u16*)((char*)d_ws + ab_bytes + bf_bytes + wq_bytes);

    cast_swz_wq<<<dim3((HQKV * DIMM / 8 + 255) / 256), 256, 0, stream>>>(qkv_w, wq);
    cast_f32_to_bf16<<<dim3(64), 256, 0, stream>>>(proj_w, wp, (long)(DIMM * DHTOT / 8));
    bias_expand<<<dim3((NH * TOK * TOK + 255) / 256), 256, 0, stream>>>(attn_bias, bias_idxs, bias_full, n_off);

    fused_qkv_attn<<<dim3(Btot), 512, 0, stream>>>(x, wq, qkv_b, bias_full, ab);

    gemm_bf16_nt<<<dim3(Mtot / 128, DIMM / 128), 256, 0, stream>>>(
        ab, wp, proj_b, (float*)d_out, Mtot, DIMM, DHTOT);
}

// Round 7
// 796.571 us; speedup vs baseline: 3.3953x; 3.3953x over previous
//
#include <hip/hip_runtime.h>
#include <cstddef>
#include <cstdint>

#define TOK    49      // tokens (7x7)
#define KD     32      // key dim
#define NH     8       // heads
#define DHEAD  128     // v head dim
#define HQKV   1536    // qkv channels
#define DHTOT  1024    // NH*DHEAD
#define DIMM   384     // model dim

typedef unsigned short u16;
typedef float  f32x4  __attribute__((ext_vector_type(4)));
typedef __bf16 bf16x8 __attribute__((ext_vector_type(8)));

typedef const __attribute__((address_space(1))) void gas_void;
typedef __attribute__((address_space(3))) void las_void;

static __device__ __forceinline__ u16 f2bf(float f) {
    unsigned int u = __builtin_bit_cast(unsigned int, f);
    return (u16)((u + 0x7fffu + ((u >> 16) & 1u)) >> 16);   // RNE
}

// XOR-swizzled index into a row-major [*][64] bf16 image: 8-short (16B) slots,
// slot ^= (row&7). Same formula on global write (GEMM epilogue) and LDS read
// (attn frags) — staging is a linear copy, so the images coincide.
static __device__ __forceinline__ int swz(int row, int c) {
    return (row << 6) + ((((c >> 3) ^ (row & 7)) << 3) | (c & 7));
}

// Bijective XCD-chunked remap (m204): hardware round-robins bid%8 across XCDs;
// give each XCD a CONTIGUOUS run of logical wgids so consecutive wgids (which
// share an A-panel when bn is fastest) hit the same per-XCD L2.
static __device__ __forceinline__ int xcd_chunk(int bid, int nwg) {
    const int xcd = bid & 7, slot = bid >> 3;
    const int q = nwg >> 3, r = nwg & 7;
    return (xcd < r ? xcd * (q + 1) : r * (q + 1) + (xcd - r) * q) + slot;
}

// ---------------------------------------------------------------------------
// fp32 -> bf16 cast, 8 elems/thread/iter, grid-stride. n8 = count/8.
// ---------------------------------------------------------------------------
__global__ __launch_bounds__(256)
void cast_f32_to_bf16(const float* __restrict__ in, u16* __restrict__ out, long n8)
{
    long i = (long)blockIdx.x * 256 + threadIdx.x;
    const long stride = (long)gridDim.x * 256;
    for (; i < n8; i += stride) {
        float4 v0 = reinterpret_cast<const float4*>(in)[i * 2];
        float4 v1 = reinterpret_cast<const float4*>(in)[i * 2 + 1];
        uint4 o;
        o.x = f2bf(v0.x) | ((unsigned)f2bf(v0.y) << 16);
        o.y = f2bf(v0.z) | ((unsigned)f2bf(v0.w) << 16);
        o.z = f2bf(v1.x) | ((unsigned)f2bf(v1.y) << 16);
        o.w = f2bf(v1.z) | ((unsigned)f2bf(v1.w) << 16);
        reinterpret_cast<uint4*>(out)[i] = o;
    }
}

// ---------------------------------------------------------------------------
// bias_full[h][n*49+m] = attn_bias[h][bias_idxs[n*49+m]]
// ---------------------------------------------------------------------------
__global__ __launch_bounds__(256)
void bias_expand(const float* __restrict__ attn_bias, const int* __restrict__ idxs,
                 float* __restrict__ bias_full, int n_off)
{
    int i = blockIdx.x * 256 + threadIdx.x;
    if (i < NH * TOK * TOK) {
        int h = i / (TOK * TOK), s = i - h * (TOK * TOK);
        bias_full[i] = attn_bias[h * n_off + idxs[s]];
    }
}

// ---------------------------------------------------------------------------
// QKV GEMM: [M,384] @ [1536,384]^T + bias, routing epilogue:
//   q,k -> qkb[(b*8+h)][64x64 bf16 swz]  (q c=0..31, k c=32..63)
//   v   -> vt [(b*8+h)][128(d) x 64(n) swz]  (transposed)
// 1-D grid, XCD-chunked, bn fastest (12 bn-tiles share each A-panel in L2).
// ---------------------------------------------------------------------------
__global__ __launch_bounds__(256)
void gemm_qkv(const u16* __restrict__ A,      // [M][384] bf16
              const u16* __restrict__ W,      // [1536][384] bf16
              const float* __restrict__ bias, // [1536]
              u16* __restrict__ qkb, u16* __restrict__ vt, int M)
{
    const int K = DIMM;
    const int NB = HQKV / 128;                 // 12
    const int nwg = (M / 128) * NB;
    const int wgid = xcd_chunk(blockIdx.x, nwg);
    const int bm = (wgid / NB) * 128;
    const int bn = (wgid % NB) * 128;

    __shared__ u16 Alds[128 * 64];
    __shared__ u16 Blds[128 * 64];

    const int t    = threadIdx.x;
    const int lane = t & 63;
    const int wv   = t >> 6;
    const int wr   = wv >> 1;
    const int wc   = wv & 1;

    const int lrow = lane >> 3;
    const int lcol = (lane & 7) * 8;
    const int frow = lane & 15;
    const int fk   = (lane >> 4) * 8;

    f32x4 acc[4][4];
    #pragma unroll
    for (int mi = 0; mi < 4; ++mi)
        #pragma unroll
        for (int ni = 0; ni < 4; ++ni) acc[mi][ni] = (f32x4)0.0f;

    for (int k0 = 0; k0 < K; k0 += 64) {
        #pragma unroll
        for (int i = 0; i < 4; ++i) {
            const int c   = i * 4 + wv;
            const int row = c * 8 + lrow;
            __builtin_amdgcn_global_load_lds((gas_void*)(A + (size_t)(bm + row) * K + k0 + lcol),
                                             (las_void*)(Alds + c * 512), 16, 0, 0);
            __builtin_amdgcn_global_load_lds((gas_void*)(W + (size_t)(bn + row) * K + k0 + lcol),
                                             (las_void*)(Blds + c * 512), 16, 0, 0);
        }
        __syncthreads();
        #pragma unroll
        for (int ks = 0; ks < 64; ks += 32) {
            bf16x8 af[4], bf[4];
            #pragma unroll
            for (int mi = 0; mi < 4; ++mi)
                af[mi] = *reinterpret_cast<const bf16x8*>(&Alds[(wr * 64 + mi * 16 + frow) * 64 + ks + fk]);
            #pragma unroll
            for (int ni = 0; ni < 4; ++ni)
                bf[ni] = *reinterpret_cast<const bf16x8*>(&Blds[(wc * 64 + ni * 16 + frow) * 64 + ks + fk]);
            #pragma unroll
            for (int mi = 0; mi < 4; ++mi)
                #pragma unroll
                for (int ni = 0; ni < 4; ++ni)
                    acc[mi][ni] = __builtin_amdgcn_mfma_f32_16x16x32_bf16(af[mi], bf[ni], acc[mi][ni], 0, 0, 0);
        }
        __syncthreads();
    }

    const int rbase = (lane >> 4) * 4;
    #pragma unroll
    for (int ni = 0; ni < 4; ++ni) {
        const int col = bn + wc * 64 + ni * 16 + frow;   // qkv channel
        const float bv = bias[col];
        const int h = col / 192;
        const int r = col - h * 192;
        #pragma unroll
        for (int mi = 0; mi < 4; ++mi) {
            #pragma unroll
            for (int j = 0; j < 4; ++j) {
                const int row = bm + wr * 64 + mi * 16 + rbase + j;   // token index
                const int bb = row / TOK;
                const int n  = row - bb * TOK;
                const u16 val = f2bf(acc[mi][ni][j] + bv);
                if (r < 64) {
                    qkb[(size_t)(bb * NH + h) * 4096 + swz(n, r)] = val;
                } else {
                    vt[(size_t)(bb * NH + h) * 8192 + swz(r - 64, n)] = val;
                }
            }
        }
    }
}

// ---------------------------------------------------------------------------
// Proj GEMM: C[M,N] = A @ W^T + bias, fp32 out. Same XCD-chunked 1-D grid.
// ---------------------------------------------------------------------------
__global__ __launch_bounds__(256)
void gemm_bf16_nt(const u16* __restrict__ A, const u16* __restrict__ W,
                  const float* __restrict__ bias, float* __restrict__ C,
                  int M, int N, int K)
{
    const int NB = N / 128;
    const int nwg = (M / 128) * NB;
    const int wgid = xcd_chunk(blockIdx.x, nwg);
    const int bm = (wgid / NB) * 128;
    const int bn = (wgid % NB) * 128;

    __shared__ u16 Alds[128 * 64];
    __shared__ u16 Blds[128 * 64];

    const int t    = threadIdx.x;
    const int lane = t & 63;
    const int wv   = t >> 6;
    const int wr   = wv >> 1;
    const int wc   = wv & 1;

    const int lrow = lane >> 3;
    const int lcol = (lane & 7) * 8;
    const int frow = lane & 15;
    const int fk   = (lane >> 4) * 8;

    f32x4 acc[4][4];
    #pragma unroll
    for (int mi = 0; mi < 4; ++mi)
        #pragma unroll
        for (int ni = 0; ni < 4; ++ni) acc[mi][ni] = (f32x4)0.0f;

    for (int k0 = 0; k0 < K; k0 += 64) {
        #pragma unroll
        for (int i = 0; i < 4; ++i) {
            const int c   = i * 4 + wv;
            const int row = c * 8 + lrow;
            __builtin_amdgcn_global_load_lds((gas_void*)(A + (size_t)(bm + row) * K + k0 + lcol),
                                             (las_void*)(Alds + c * 512), 16, 0, 0);
            __builtin_amdgcn_global_load_lds((gas_void*)(W + (size_t)(bn + row) * K + k0 + lcol),
                                             (las_void*)(Blds + c * 512), 16, 0, 0);
        }
        __syncthreads();
        #pragma unroll
        for (int ks = 0; ks < 64; ks += 32) {
            bf16x8 af[4], bf[4];
            #pragma unroll
            for (int mi = 0; mi < 4; ++mi)
                af[mi] = *reinterpret_cast<const bf16x8*>(&Alds[(wr * 64 + mi * 16 + frow) * 64 + ks + fk]);
            #pragma unroll
            for (int ni = 0; ni < 4; ++ni)
                bf[ni] = *reinterpret_cast<const bf16x8*>(&Blds[(wc * 64 + ni * 16 + frow) * 64 + ks + fk]);
            #pragma unroll
            for (int mi = 0; mi < 4; ++mi)
                #pragma unroll
                for (int ni = 0; ni < 4; ++ni)
                    acc[mi][ni] = __builtin_amdgcn_mfma_f32_16x16x32_bf16(af[mi], bf[ni], acc[mi][ni], 0, 0, 0);
        }
        __syncthreads();
    }

    const int rbase = (lane >> 4) * 4;
    #pragma unroll
    for (int ni = 0; ni < 4; ++ni) {
        const int col = bn + wc * 64 + ni * 16 + frow;
        const float bv = bias[col];
        #pragma unroll
        for (int mi = 0; mi < 4; ++mi) {
            #pragma unroll
            for (int j = 0; j < 4; ++j) {
                const int row = bm + wr * 64 + mi * 16 + rbase + j;
                C[(size_t)row * N + col] = acc[mi][ni][j] + bv;
            }
        }
    }
}

// ---------------------------------------------------------------------------
// MFMA attention (validated r5). One block per (b,h), 256 threads / 4 waves.
// ---------------------------------------------------------------------------
__global__ __launch_bounds__(256)
void attn_mfma(const u16* __restrict__ qkb, const u16* __restrict__ vt,
               const float* __restrict__ bias_full,   // [NH][49*49]
               u16* __restrict__ ab)                  // [Mc][1024]
{
    __shared__ __align__(16) u16  QKs[64 * 64];
    __shared__ __align__(16) u16  Vts[128 * 64];
    __shared__ __align__(16) float S[64 * 80];
    __shared__ __align__(16) u16  Ps[64 * 64];

    const int t    = threadIdx.x;
    const int lane = t & 63;
    const int w    = t >> 6;
    const int fr   = lane & 15;
    const int fg   = lane >> 4;
    const int b    = blockIdx.x;
    const int h    = blockIdx.y;
    const int bh   = b * NH + h;

    const u16* gq = qkb + (size_t)bh * 4096;
    const u16* gv = vt  + (size_t)bh * 8192;
    #pragma unroll
    for (int i = 0; i < 2; ++i)
        __builtin_amdgcn_global_load_lds((gas_void*)(gq + (i * 256 + t) * 8),
                                         (las_void*)(QKs + (i * 256 + w * 64) * 8), 16, 0, 0);
    #pragma unroll
    for (int i = 0; i < 4; ++i)
        __builtin_amdgcn_global_load_lds((gas_void*)(gv + (i * 256 + t) * 8),
                                         (las_void*)(Vts + (i * 256 + w * 64) * 8), 16, 0, 0);
    __syncthreads();

    bf16x8 qf = *reinterpret_cast<const bf16x8*>(&QKs[swz(16 * w + fr, fg * 8)]);
    f32x4 sacc[4];
    #pragma unroll
    for (int nj = 0; nj < 4; ++nj) {
        bf16x8 kf = *reinterpret_cast<const bf16x8*>(&QKs[swz(16 * nj + fr, 32 + fg * 8)]);
        sacc[nj] = __builtin_amdgcn_mfma_f32_16x16x32_bf16(qf, kf, (f32x4)0.0f, 0, 0, 0);
    }

    const float scale = 0.17677669529663687f;  // 32^-0.5
    const float* bh_bias = bias_full + h * (TOK * TOK);
    #pragma unroll
    for (int nj = 0; nj < 4; ++nj) {
        #pragma unroll
        for (int j = 0; j < 4; ++j) {
            const int row = 16 * w + fg * 4 + j;
            const int col = 16 * nj + fr;
            const int rn = row < TOK ? row : TOK - 1;
            const int cm = col < TOK ? col : TOK - 1;
            S[row * 80 + col] = sacc[nj][j] * scale + bh_bias[rn * TOK + cm];
        }
    }
    __syncthreads();

    {
        const int n = t >> 2, j = t & 3;
        const float* Sr = &S[n * 80];
        float v[16];
        #pragma unroll
        for (int e = 0; e < 8; ++e) v[e]     = Sr[8 * j + e];
        #pragma unroll
        for (int e = 0; e < 8; ++e) v[8 + e] = Sr[32 + 8 * j + e];

        float mx = -1e30f;
        #pragma unroll
        for (int e = 0; e < 8; ++e) mx = fmaxf(mx, v[e]);
        #pragma unroll
        for (int e = 0; e < 8; ++e)
            if (32 + 8 * j + e < TOK) mx = fmaxf(mx, v[8 + e]);
        mx = fmaxf(mx, __shfl_xor(mx, 1, 4));
        mx = fmaxf(mx, __shfl_xor(mx, 2, 4));

        float sum = 0.f;
        #pragma unroll
        for (int e = 0; e < 8; ++e) { v[e] = __expf(v[e] - mx); sum += v[e]; }
        #pragma unroll
        for (int e = 0; e < 8; ++e) {
            const float ev = (32 + 8 * j + e < TOK) ? __expf(v[8 + e] - mx) : 0.f;
            v[8 + e] = ev; sum += ev;
        }
        sum += __shfl_xor(sum, 1, 4);
        sum += __shfl_xor(sum, 2, 4);
        const float inv = 1.f / sum;

        uint4 o;
        o.x = f2bf(v[0] * inv)  | ((unsigned)f2bf(v[1] * inv)  << 16);
        o.y = f2bf(v[2] * inv)  | ((unsigned)f2bf(v[3] * inv)  << 16);
        o.z = f2bf(v[4] * inv)  | ((unsigned)f2bf(v[5] * inv)  << 16);
        o.w = f2bf(v[6] * inv)  | ((unsigned)f2bf(v[7] * inv)  << 16);
        *reinterpret_cast<uint4*>(&Ps[swz(n, 8 * j)]) = o;
        o.x = f2bf(v[8] * inv)  | ((unsigned)f2bf(v[9] * inv)  << 16);
        o.y = f2bf(v[10] * inv) | ((unsigned)f2bf(v[11] * inv) << 16);
        o.z = f2bf(v[12] * inv) | ((unsigned)f2bf(v[13] * inv) << 16);
        o.w = f2bf(v[14] * inv) | ((unsigned)f2bf(v[15] * inv) << 16);
        *reinterpret_cast<uint4*>(&Ps[swz(n, 32 + 8 * j)]) = o;
    }
    __syncthreads();

    f32x4 oacc[8];
    #pragma unroll
    for (int nj = 0; nj < 8; ++nj) oacc[nj] = (f32x4)0.0f;
    #pragma unroll
    for (int ks = 0; ks < 2; ++ks) {
        bf16x8 pf = *reinterpret_cast<const bf16x8*>(&Ps[swz(16 * w + fr, ks * 32 + fg * 8)]);
        #pragma unroll
        for (int nj = 0; nj < 8; ++nj) {
            bf16x8 vf = *reinterpret_cast<const bf16x8*>(&Vts[swz(16 * nj + fr, ks * 32 + fg * 8)]);
            oacc[nj] = __builtin_amdgcn_mfma_f32_16x16x32_bf16(pf, vf, oacc[nj], 0, 0, 0);
        }
    }

    #pragma unroll
    for (int nj = 0; nj < 8; ++nj) {
        const int d = 16 * nj + fr;
        #pragma unroll
        for (int j = 0; j < 4; ++j) {
            const int n = 16 * w + fg * 4 + j;
            if (n < TOK)
                ab[((size_t)b * TOK + n) * DHTOT + h * DHEAD + d] = f2bf(oacc[nj][j]);
        }
    }
}

// ---------------------------------------------------------------------------
extern "C" void kernel_launch(void* const* d_in, const int* in_sizes, int n_in,
                              void* d_out, int out_size, void* d_ws, size_t ws_size,
                              hipStream_t stream)
{
    const float* x         = (const float*)d_in[0];
    const float* qkv_w     = (const float*)d_in[1];
    const float* qkv_b     = (const float*)d_in[2];
    const float* proj_w    = (const float*)d_in[3];
    const float* proj_b    = (const float*)d_in[4];
    const float* attn_bias = (const float*)d_in[5];
    const int*   bias_idxs = (const int*)d_in[6];

    const int Mtot  = in_sizes[0] / DIMM;            // 100352
    const int Btot  = Mtot / TOK;                    // 2048
    const int n_off = in_sizes[5] / NH;              // 49

    const size_t nWq = (size_t)HQKV * DIMM;
    const size_t nWp = (size_t)DIMM * DHTOT;
    float* bias_full = (float*)d_ws;                           // 76832 B
    u16*   wq        = (u16*)((char*)d_ws + 76832);
    u16*   wp        = wq + nWq;
    u16*   dyn       = wp + nWp;
    const size_t fixed_bytes = 76832 + (nWq + nWp) * sizeof(u16);
    // per-batch: xb 49*384*2 + qkb 8*4096*2 + vt 8*8192*2 + ab 49*1024*2
    const size_t per_batch = (size_t)TOK * DIMM * 2 + NH * 4096 * 2 + NH * 8192 * 2 + (size_t)TOK * DHTOT * 2;

    if (ws_size <= fixed_bytes) return;
    long BcL = (long)((ws_size - fixed_bytes) / per_batch);
    int Bc = (int)((BcL / 128) * 128);       // keep Mc multiple of 128
    if (Bc <= 0) return;
    if (Bc > Btot) Bc = Btot;                // round-3 evidence: ws >= 1.027 GB -> single chunk

    cast_f32_to_bf16<<<dim3(64), 256, 0, stream>>>(qkv_w, wq, (long)(nWq / 8));
    cast_f32_to_bf16<<<dim3(64), 256, 0, stream>>>(proj_w, wp, (long)(nWp / 8));
    bias_expand<<<dim3((NH * TOK * TOK + 255) / 256), 256, 0, stream>>>(attn_bias, bias_idxs, bias_full, n_off);

    for (int b0 = 0; b0 < Btot; b0 += Bc) {
        const int bc = (b0 + Bc <= Btot) ? Bc : (Btot - b0);   // multiple of 128
        const int Mc = bc * TOK;

        u16* xb  = dyn;
        u16* qkb = xb  + (size_t)Bc * TOK * DIMM;
        u16* vtb = qkb + (size_t)Bc * NH * 4096;
        u16* abb = vtb + (size_t)Bc * NH * 8192;

        const float* xc   = x + (size_t)b0 * TOK * DIMM;
        float*       outc = (float*)d_out + (size_t)b0 * TOK * DIMM;

        cast_f32_to_bf16<<<dim3(2048), 256, 0, stream>>>(xc, xb, (long)Mc * DIMM / 8);

        gemm_qkv<<<dim3((Mc / 128) * (HQKV / 128)), 256, 0, stream>>>(xb, wq, qkv_b, qkb, vtb, Mc);

        attn_mfma<<<dim3(bc, NH), 256, 0, stream>>>(qkb, vtb, bias_full, abb);

        gemm_bf16_nt<<<dim3((Mc / 128) * (DIMM / 128)), 256, 0, stream>>>(abb, wp, proj_b, outc, Mc, DIMM, DHTOT);
    }
}

// Round 8
// 783.374 us; speedup vs baseline: 3.4524x; 1.0168x over previous
//
#include <hip/hip_runtime.h>
#include <cstddef>
#include <cstdint>

#define TOK    49      // tokens (7x7)
#define KD     32      // key dim
#define NH     8       // heads
#define DHEAD  128     // v head dim
#define HQKV   1536    // qkv channels
#define DHTOT  1024    // NH*DHEAD
#define DIMM   384     // model dim

typedef unsigned short u16;
typedef float  f32x4  __attribute__((ext_vector_type(4)));
typedef __bf16 bf16x8 __attribute__((ext_vector_type(8)));

typedef const __attribute__((address_space(1))) void gas_void;
typedef __attribute__((address_space(3))) void las_void;

static __device__ __forceinline__ u16 f2bf(float f) {
    unsigned int u = __builtin_bit_cast(unsigned int, f);
    return (u16)((u + 0x7fffu + ((u >> 16) & 1u)) >> 16);   // RNE
}

// XOR-swizzled index into a row-major [*][64] bf16 image: 8-short (16B) slots,
// slot ^= (row&7). Same formula on global write (GEMM epilogue) and LDS read
// (attn frags) — staging is a linear copy, so the images coincide.
static __device__ __forceinline__ int swz(int row, int c) {
    return (row << 6) + ((((c >> 3) ^ (row & 7)) << 3) | (c & 7));
}

// Bijective XCD-chunked remap (m204): consecutive logical wgids land on the
// same XCD so bn-fastest neighbors share the A-panel in that XCD's L2.
static __device__ __forceinline__ int xcd_chunk(int bid, int nwg) {
    const int xcd = bid & 7, slot = bid >> 3;
    const int q = nwg >> 3, r = nwg & 7;
    return (xcd < r ? xcd * (q + 1) : r * (q + 1) + (xcd - r) * q) + slot;
}

// ---------------------------------------------------------------------------
// fp32 -> bf16 cast, 8 elems/thread/iter, grid-stride. n8 = count/8.
// ---------------------------------------------------------------------------
__global__ __launch_bounds__(256)
void cast_f32_to_bf16(const float* __restrict__ in, u16* __restrict__ out, long n8)
{
    long i = (long)blockIdx.x * 256 + threadIdx.x;
    const long stride = (long)gridDim.x * 256;
    for (; i < n8; i += stride) {
        float4 v0 = reinterpret_cast<const float4*>(in)[i * 2];
        float4 v1 = reinterpret_cast<const float4*>(in)[i * 2 + 1];
        uint4 o;
        o.x = f2bf(v0.x) | ((unsigned)f2bf(v0.y) << 16);
        o.y = f2bf(v0.z) | ((unsigned)f2bf(v0.w) << 16);
        o.z = f2bf(v1.x) | ((unsigned)f2bf(v1.y) << 16);
        o.w = f2bf(v1.z) | ((unsigned)f2bf(v1.w) << 16);
        reinterpret_cast<uint4*>(out)[i] = o;
    }
}

// ---------------------------------------------------------------------------
// bias_full[h][n*49+m] = attn_bias[h][bias_idxs[n*49+m]]
// ---------------------------------------------------------------------------
__global__ __launch_bounds__(256)
void bias_expand(const float* __restrict__ attn_bias, const int* __restrict__ idxs,
                 float* __restrict__ bias_full, int n_off)
{
    int i = blockIdx.x * 256 + threadIdx.x;
    if (i < NH * TOK * TOK) {
        int h = i / (TOK * TOK), s = i - h * (TOK * TOK);
        bias_full[i] = attn_bias[h * n_off + idxs[s]];
    }
}

// ---------------------------------------------------------------------------
// QKV GEMM: [M,384] @ [1536,384]^T + bias, 2-phase double-buffered K-loop
// (T3 minimum recipe: prefetch t+1 BEFORE computing t, ONE barrier per step).
// Routing epilogue: q,k -> qkb[(b*8+h)][64x64 swz]; v -> vt[(b*8+h)][128x64 swz, transposed].
// ---------------------------------------------------------------------------
__global__ __launch_bounds__(256)
void gemm_qkv(const u16* __restrict__ A,      // [M][384] bf16
              const u16* __restrict__ W,      // [1536][384] bf16
              const float* __restrict__ bias, // [1536]
              u16* __restrict__ qkb, u16* __restrict__ vt, int M)
{
    const int K = DIMM;                        // 384 -> 6 K-steps
    const int NB = HQKV / 128;                 // 12
    const int nwg = (M / 128) * NB;
    const int wgid = xcd_chunk(blockIdx.x, nwg);
    const int bm = (wgid / NB) * 128;
    const int bn = (wgid % NB) * 128;

    __shared__ u16 Alds[2][128 * 64];
    __shared__ u16 Blds[2][128 * 64];

    const int t    = threadIdx.x;
    const int lane = t & 63;
    const int wv   = t >> 6;
    const int wr   = wv >> 1;
    const int wc   = wv & 1;

    const int lrow = lane >> 3;
    const int lcol = (lane & 7) * 8;
    const int frow = lane & 15;
    const int fk   = (lane >> 4) * 8;

    f32x4 acc[4][4];
    #pragma unroll
    for (int mi = 0; mi < 4; ++mi)
        #pragma unroll
        for (int ni = 0; ni < 4; ++ni) acc[mi][ni] = (f32x4)0.0f;

    auto STAGE = [&](int buf, int k0) {
        #pragma unroll
        for (int i = 0; i < 4; ++i) {
            const int c   = i * 4 + wv;
            const int row = c * 8 + lrow;
            __builtin_amdgcn_global_load_lds((gas_void*)(A + (size_t)(bm + row) * K + k0 + lcol),
                                             (las_void*)(&Alds[buf][c * 512]), 16, 0, 0);
            __builtin_amdgcn_global_load_lds((gas_void*)(W + (size_t)(bn + row) * K + k0 + lcol),
                                             (las_void*)(&Blds[buf][c * 512]), 16, 0, 0);
        }
    };

    STAGE(0, 0);
    __syncthreads();                           // drain prologue stage

    for (int ts = 0; ts < 6; ++ts) {
        if (ts < 5) STAGE((ts + 1) & 1, (ts + 1) * 64);   // prefetch flies over compute
        const u16* Ab = Alds[ts & 1];
        const u16* Bb = Blds[ts & 1];
        #pragma unroll
        for (int ks = 0; ks < 64; ks += 32) {
            bf16x8 af[4], bf[4];
            #pragma unroll
            for (int mi = 0; mi < 4; ++mi)
                af[mi] = *reinterpret_cast<const bf16x8*>(&Ab[(wr * 64 + mi * 16 + frow) * 64 + ks + fk]);
            #pragma unroll
            for (int ni = 0; ni < 4; ++ni)
                bf[ni] = *reinterpret_cast<const bf16x8*>(&Bb[(wc * 64 + ni * 16 + frow) * 64 + ks + fk]);
            #pragma unroll
            for (int mi = 0; mi < 4; ++mi)
                #pragma unroll
                for (int ni = 0; ni < 4; ++ni)
                    acc[mi][ni] = __builtin_amdgcn_mfma_f32_16x16x32_bf16(af[mi], bf[ni], acc[mi][ni], 0, 0, 0);
        }
        __syncthreads();                       // drains prefetch; frees buf[ts&1] for ts+2
    }

    const int rbase = (lane >> 4) * 4;
    #pragma unroll
    for (int ni = 0; ni < 4; ++ni) {
        const int col = bn + wc * 64 + ni * 16 + frow;   // qkv channel
        const float bv = bias[col];
        const int h = col / 192;
        const int r = col - h * 192;
        #pragma unroll
        for (int mi = 0; mi < 4; ++mi) {
            #pragma unroll
            for (int j = 0; j < 4; ++j) {
                const int row = bm + wr * 64 + mi * 16 + rbase + j;   // token index
                const int bb = row / TOK;
                const int n  = row - bb * TOK;
                const u16 val = f2bf(acc[mi][ni][j] + bv);
                if (r < 64) {
                    qkb[(size_t)(bb * NH + h) * 4096 + swz(n, r)] = val;
                } else {
                    vt[(size_t)(bb * NH + h) * 8192 + swz(r - 64, n)] = val;
                }
            }
        }
    }
}

// ---------------------------------------------------------------------------
// Proj GEMM: C[M,N] = A @ W^T + bias, fp32 out. Same 2-phase dbuf K-loop.
// ---------------------------------------------------------------------------
__global__ __launch_bounds__(256)
void gemm_bf16_nt(const u16* __restrict__ A, const u16* __restrict__ W,
                  const float* __restrict__ bias, float* __restrict__ C,
                  int M, int N, int K)
{
    const int NB = N / 128;
    const int nwg = (M / 128) * NB;
    const int wgid = xcd_chunk(blockIdx.x, nwg);
    const int bm = (wgid / NB) * 128;
    const int bn = (wgid % NB) * 128;

    __shared__ u16 Alds[2][128 * 64];
    __shared__ u16 Blds[2][128 * 64];

    const int t    = threadIdx.x;
    const int lane = t & 63;
    const int wv   = t >> 6;
    const int wr   = wv >> 1;
    const int wc   = wv & 1;

    const int lrow = lane >> 3;
    const int lcol = (lane & 7) * 8;
    const int frow = lane & 15;
    const int fk   = (lane >> 4) * 8;

    f32x4 acc[4][4];
    #pragma unroll
    for (int mi = 0; mi < 4; ++mi)
        #pragma unroll
        for (int ni = 0; ni < 4; ++ni) acc[mi][ni] = (f32x4)0.0f;

    auto STAGE = [&](int buf, int k0) {
        #pragma unroll
        for (int i = 0; i < 4; ++i) {
            const int c   = i * 4 + wv;
            const int row = c * 8 + lrow;
            __builtin_amdgcn_global_load_lds((gas_void*)(A + (size_t)(bm + row) * K + k0 + lcol),
                                             (las_void*)(&Alds[buf][c * 512]), 16, 0, 0);
            __builtin_amdgcn_global_load_lds((gas_void*)(W + (size_t)(bn + row) * K + k0 + lcol),
                                             (las_void*)(&Blds[buf][c * 512]), 16, 0, 0);
        }
    };

    const int NT = K / 64;
    STAGE(0, 0);
    __syncthreads();

    for (int ts = 0; ts < NT; ++ts) {
        if (ts < NT - 1) STAGE((ts + 1) & 1, (ts + 1) * 64);
        const u16* Ab = Alds[ts & 1];
        const u16* Bb = Blds[ts & 1];
        #pragma unroll
        for (int ks = 0; ks < 64; ks += 32) {
            bf16x8 af[4], bf[4];
            #pragma unroll
            for (int mi = 0; mi < 4; ++mi)
                af[mi] = *reinterpret_cast<const bf16x8*>(&Ab[(wr * 64 + mi * 16 + frow) * 64 + ks + fk]);
            #pragma unroll
            for (int ni = 0; ni < 4; ++ni)
                bf[ni] = *reinterpret_cast<const bf16x8*>(&Bb[(wc * 64 + ni * 16 + frow) * 64 + ks + fk]);
            #pragma unroll
            for (int mi = 0; mi < 4; ++mi)
                #pragma unroll
                for (int ni = 0; ni < 4; ++ni)
                    acc[mi][ni] = __builtin_amdgcn_mfma_f32_16x16x32_bf16(af[mi], bf[ni], acc[mi][ni], 0, 0, 0);
        }
        __syncthreads();
    }

    const int rbase = (lane >> 4) * 4;
    #pragma unroll
    for (int ni = 0; ni < 4; ++ni) {
        const int col = bn + wc * 64 + ni * 16 + frow;
        const float bv = bias[col];
        #pragma unroll
        for (int mi = 0; mi < 4; ++mi) {
            #pragma unroll
            for (int j = 0; j < 4; ++j) {
                const int row = bm + wr * 64 + mi * 16 + rbase + j;
                C[(size_t)row * N + col] = acc[mi][ni][j] + bv;
            }
        }
    }
}

// ---------------------------------------------------------------------------
// MFMA attention (validated r5/r7). One block per (b,h), 256 threads / 4 waves.
// ---------------------------------------------------------------------------
__global__ __launch_bounds__(256)
void attn_mfma(const u16* __restrict__ qkb, const u16* __restrict__ vt,
               const float* __restrict__ bias_full,   // [NH][49*49]
               u16* __restrict__ ab)                  // [Mc][1024]
{
    __shared__ __align__(16) u16  QKs[64 * 64];
    __shared__ __align__(16) u16  Vts[128 * 64];
    __shared__ __align__(16) float S[64 * 80];
    __shared__ __align__(16) u16  Ps[64 * 64];

    const int t    = threadIdx.x;
    const int lane = t & 63;
    const int w    = t >> 6;
    const int fr   = lane & 15;
    const int fg   = lane >> 4;
    const int b    = blockIdx.x;
    const int h    = blockIdx.y;
    const int bh   = b * NH + h;

    const u16* gq = qkb + (size_t)bh * 4096;
    const u16* gv = vt  + (size_t)bh * 8192;
    #pragma unroll
    for (int i = 0; i < 2; ++i)
        __builtin_amdgcn_global_load_lds((gas_void*)(gq + (i * 256 + t) * 8),
                                         (las_void*)(QKs + (i * 256 + w * 64) * 8), 16, 0, 0);
    #pragma unroll
    for (int i = 0; i < 4; ++i)
        __builtin_amdgcn_global_load_lds((gas_void*)(gv + (i * 256 + t) * 8),
                                         (las_void*)(Vts + (i * 256 + w * 64) * 8), 16, 0, 0);
    __syncthreads();

    bf16x8 qf = *reinterpret_cast<const bf16x8*>(&QKs[swz(16 * w + fr, fg * 8)]);
    f32x4 sacc[4];
    #pragma unroll
    for (int nj = 0; nj < 4; ++nj) {
        bf16x8 kf = *reinterpret_cast<const bf16x8*>(&QKs[swz(16 * nj + fr, 32 + fg * 8)]);
        sacc[nj] = __builtin_amdgcn_mfma_f32_16x16x32_bf16(qf, kf, (f32x4)0.0f, 0, 0, 0);
    }

    const float scale = 0.17677669529663687f;  // 32^-0.5
    const float* bh_bias = bias_full + h * (TOK * TOK);
    #pragma unroll
    for (int nj = 0; nj < 4; ++nj) {
        #pragma unroll
        for (int j = 0; j < 4; ++j) {
            const int row = 16 * w + fg * 4 + j;
            const int col = 16 * nj + fr;
            const int rn = row < TOK ? row : TOK - 1;
            const int cm = col < TOK ? col : TOK - 1;
            S[row * 80 + col] = sacc[nj][j] * scale + bh_bias[rn * TOK + cm];
        }
    }
    __syncthreads();

    {
        const int n = t >> 2, j = t & 3;
        const float* Sr = &S[n * 80];
        float v[16];
        #pragma unroll
        for (int e = 0; e < 8; ++e) v[e]     = Sr[8 * j + e];
        #pragma unroll
        for (int e = 0; e < 8; ++e) v[8 + e] = Sr[32 + 8 * j + e];

        float mx = -1e30f;
        #pragma unroll
        for (int e = 0; e < 8; ++e) mx = fmaxf(mx, v[e]);
        #pragma unroll
        for (int e = 0; e < 8; ++e)
            if (32 + 8 * j + e < TOK) mx = fmaxf(mx, v[8 + e]);
        mx = fmaxf(mx, __shfl_xor(mx, 1, 4));
        mx = fmaxf(mx, __shfl_xor(mx, 2, 4));

        float sum = 0.f;
        #pragma unroll
        for (int e = 0; e < 8; ++e) { v[e] = __expf(v[e] - mx); sum += v[e]; }
        #pragma unroll
        for (int e = 0; e < 8; ++e) {
            const float ev = (32 + 8 * j + e < TOK) ? __expf(v[8 + e] - mx) : 0.f;
            v[8 + e] = ev; sum += ev;
        }
        sum += __shfl_xor(sum, 1, 4);
        sum += __shfl_xor(sum, 2, 4);
        const float inv = 1.f / sum;

        uint4 o;
        o.x = f2bf(v[0] * inv)  | ((unsigned)f2bf(v[1] * inv)  << 16);
        o.y = f2bf(v[2] * inv)  | ((unsigned)f2bf(v[3] * inv)  << 16);
        o.z = f2bf(v[4] * inv)  | ((unsigned)f2bf(v[5] * inv)  << 16);
        o.w = f2bf(v[6] * inv)  | ((unsigned)f2bf(v[7] * inv)  << 16);
        *reinterpret_cast<uint4*>(&Ps[swz(n, 8 * j)]) = o;
        o.x = f2bf(v[8] * inv)  | ((unsigned)f2bf(v[9] * inv)  << 16);
        o.y = f2bf(v[10] * inv) | ((unsigned)f2bf(v[11] * inv) << 16);
        o.z = f2bf(v[12] * inv) | ((unsigned)f2bf(v[13] * inv) << 16);
        o.w = f2bf(v[14] * inv) | ((unsigned)f2bf(v[15] * inv) << 16);
        *reinterpret_cast<uint4*>(&Ps[swz(n, 32 + 8 * j)]) = o;
    }
    __syncthreads();

    f32x4 oacc[8];
    #pragma unroll
    for (int nj = 0; nj < 8; ++nj) oacc[nj] = (f32x4)0.0f;
    #pragma unroll
    for (int ks = 0; ks < 2; ++ks) {
        bf16x8 pf = *reinterpret_cast<const bf16x8*>(&Ps[swz(16 * w + fr, ks * 32 + fg * 8)]);
        #pragma unroll
        for (int nj = 0; nj < 8; ++nj) {
            bf16x8 vf = *reinterpret_cast<const bf16x8*>(&Vts[swz(16 * nj + fr, ks * 32 + fg * 8)]);
            oacc[nj] = __builtin_amdgcn_mfma_f32_16x16x32_bf16(pf, vf, oacc[nj], 0, 0, 0);
        }
    }

    #pragma unroll
    for (int nj = 0; nj < 8; ++nj) {
        const int d = 16 * nj + fr;
        #pragma unroll
        for (int j = 0; j < 4; ++j) {
            const int n = 16 * w + fg * 4 + j;
            if (n < TOK)
                ab[((size_t)b * TOK + n) * DHTOT + h * DHEAD + d] = f2bf(oacc[nj][j]);
        }
    }
}

// ---------------------------------------------------------------------------
extern "C" void kernel_launch(void* const* d_in, const int* in_sizes, int n_in,
                              void* d_out, int out_size, void* d_ws, size_t ws_size,
                              hipStream_t stream)
{
    const float* x         = (const float*)d_in[0];
    const float* qkv_w     = (const float*)d_in[1];
    const float* qkv_b     = (const float*)d_in[2];
    const float* proj_w    = (const float*)d_in[3];
    const float* proj_b    = (const float*)d_in[4];
    const float* attn_bias = (const float*)d_in[5];
    const int*   bias_idxs = (const int*)d_in[6];

    const int Mtot  = in_sizes[0] / DIMM;            // 100352
    const int Btot  = Mtot / TOK;                    // 2048
    const int n_off = in_sizes[5] / NH;              // 49

    const size_t nWq = (size_t)HQKV * DIMM;
    const size_t nWp = (size_t)DIMM * DHTOT;
    float* bias_full = (float*)d_ws;                           // 76832 B
    u16*   wq        = (u16*)((char*)d_ws + 76832);
    u16*   wp        = wq + nWq;
    u16*   dyn       = wp + nWp;
    const size_t fixed_bytes = 76832 + (nWq + nWp) * sizeof(u16);
    // per-batch: xb 49*384*2 + qkb 8*4096*2 + vt 8*8192*2 + ab 49*1024*2
    const size_t per_batch = (size_t)TOK * DIMM * 2 + NH * 4096 * 2 + NH * 8192 * 2 + (size_t)TOK * DHTOT * 2;

    if (ws_size <= fixed_bytes) return;
    long BcL = (long)((ws_size - fixed_bytes) / per_batch);
    int Bc = (int)((BcL / 128) * 128);       // keep Mc multiple of 128
    if (Bc <= 0) return;
    if (Bc > Btot) Bc = Btot;                // round-3 evidence: single chunk in practice

    cast_f32_to_bf16<<<dim3(64), 256, 0, stream>>>(qkv_w, wq, (long)(nWq / 8));
    cast_f32_to_bf16<<<dim3(64), 256, 0, stream>>>(proj_w, wp, (long)(nWp / 8));
    bias_expand<<<dim3((NH * TOK * TOK + 255) / 256), 256, 0, stream>>>(attn_bias, bias_idxs, bias_full, n_off);

    for (int b0 = 0; b0 < Btot; b0 += Bc) {
        const int bc = (b0 + Bc <= Btot) ? Bc : (Btot - b0);   // multiple of 128
        const int Mc = bc * TOK;

        u16* xb  = dyn;
        u16* qkb = xb  + (size_t)Bc * TOK * DIMM;
        u16* vtb = qkb + (size_t)Bc * NH * 4096;
        u16* abb = vtb + (size_t)Bc * NH * 8192;

        const float* xc   = x + (size_t)b0 * TOK * DIMM;
        float*       outc = (float*)d_out + (size_t)b0 * TOK * DIMM;

        cast_f32_to_bf16<<<dim3(2048), 256, 0, stream>>>(xc, xb, (long)Mc * DIMM / 8);

        gemm_qkv<<<dim3((Mc / 128) * (HQKV / 128)), 256, 0, stream>>>(xb, wq, qkv_b, qkb, vtb, Mc);

        attn_mfma<<<dim3(bc, NH), 256, 0, stream>>>(qkb, vtb, bias_full, abb);

        gemm_bf16_nt<<<dim3((Mc / 128) * (DIMM / 128)), 256, 0, stream>>>(abb, wp, proj_b, outc, Mc, DIMM, DHTOT);
    }
}

// Round 10
// 758.515 us; speedup vs baseline: 3.5656x; 1.0328x over previous
//
#include <hip/hip_runtime.h>
#include <cstddef>
#include <cstdint>

#define TOK    49      // tokens (7x7)
#define KD     32      // key dim
#define NH     8       // heads
#define DHEAD  128     // v head dim
#define HQKV   1536    // qkv channels
#define DHTOT  1024    // NH*DHEAD
#define DIMM   384     // model dim

typedef unsigned short u16;
typedef float  f32x4  __attribute__((ext_vector_type(4)));
typedef __bf16 bf16x8 __attribute__((ext_vector_type(8)));

typedef const __attribute__((address_space(1))) void gas_void;
typedef __attribute__((address_space(3))) void las_void;

static __device__ __forceinline__ u16 f2bf(float f) {
    unsigned int u = __builtin_bit_cast(unsigned int, f);
    return (u16)((u + 0x7fffu + ((u >> 16) & 1u)) >> 16);   // RNE
}

// XOR-swizzled index into a row-major [*][64] bf16 image (attn q/k/v images):
// 8-short (16B) slots, slot ^= (row&7).
static __device__ __forceinline__ int swz(int row, int c) {
    return (row << 6) + ((((c >> 3) ^ (row & 7)) << 3) | (c & 7));
}

// Bijective XCD-chunked remap (m204).
static __device__ __forceinline__ int xcd_chunk(int bid, int nwg) {
    const int xcd = bid & 7, slot = bid >> 3;
    const int q = nwg >> 3, r = nwg & 7;
    return (xcd < r ? xcd * (q + 1) : r * (q + 1) + (xcd - r) * q) + slot;
}

// ---------------------------------------------------------------------------
// fp32 -> bf16 cast with T2 pre-swizzle: within each 64-col panel, 16B slot
// s of row r is stored at slot s^(r&7). GEMM staging copies 16B chunks
// linearly into LDS, so the LDS tile carries the swizzle; frag reads XOR it.
// K8 = K/8 (row length in 8-elem chunks).
// ---------------------------------------------------------------------------
__global__ __launch_bounds__(256)
void cast_swz(const float* __restrict__ in, u16* __restrict__ out, int K8, long nchunk)
{
    long i = (long)blockIdx.x * 256 + threadIdx.x;
    const long stride = (long)gridDim.x * 256;
    for (; i < nchunk; i += stride) {
        const long row = i / K8;
        const int  c8  = (int)(i - row * K8);
        const int  slot = c8 & 7, tpan = c8 >> 3;
        float4 v0 = reinterpret_cast<const float4*>(in)[i * 2];
        float4 v1 = reinterpret_cast<const float4*>(in)[i * 2 + 1];
        uint4 o;
        o.x = f2bf(v0.x) | ((unsigned)f2bf(v0.y) << 16);
        o.y = f2bf(v0.z) | ((unsigned)f2bf(v0.w) << 16);
        o.z = f2bf(v1.x) | ((unsigned)f2bf(v1.y) << 16);
        o.w = f2bf(v1.z) | ((unsigned)f2bf(v1.w) << 16);
        *reinterpret_cast<uint4*>(out + row * (long)K8 * 8 + tpan * 64 +
                                  ((slot ^ ((int)row & 7)) << 3)) = o;
    }
}

// ---------------------------------------------------------------------------
// bias_full[h][n*49+m] = attn_bias[h][bias_idxs[n*49+m]]
// ---------------------------------------------------------------------------
__global__ __launch_bounds__(256)
void bias_expand(const float* __restrict__ attn_bias, const int* __restrict__ idxs,
                 float* __restrict__ bias_full, int n_off)
{
    int i = blockIdx.x * 256 + threadIdx.x;
    if (i < NH * TOK * TOK) {
        int h = i / (TOK * TOK), s = i - h * (TOK * TOK);
        bias_full[i] = attn_bias[h * n_off + idxs[s]];
    }
}

// Fragment read offset in a [rows][64]-short LDS tile holding pre-swizzled
// content: original col slot = ks/8 + fg, stored at slot ^ (row&7).
static __device__ __forceinline__ int frag_off(int row, int ks8fg) {
    return (row << 6) + (((ks8fg ^ (row & 7)) << 3));
}

// ---------------------------------------------------------------------------
// QKV GEMM: [M,384] @ [1536,384]^T + bias, 2-phase dbuf, T2-swizzled LDS.
// Routing epilogue -> qkb (64x64 swz) / vt (128x64 swz, transposed).
// ---------------------------------------------------------------------------
__global__ __launch_bounds__(256)
void gemm_qkv(const u16* __restrict__ A,      // [M][384] bf16 pre-swz
              const u16* __restrict__ W,      // [1536][384] bf16 pre-swz
              const float* __restrict__ bias, // [1536]
              u16* __restrict__ qkb, u16* __restrict__ vt, int M)
{
    const int K = DIMM;                        // 384 -> 6 K-steps
    const int NB = HQKV / 128;                 // 12
    const int nwg = (M / 128) * NB;
    const int wgid = xcd_chunk(blockIdx.x, nwg);
    const int bm = (wgid / NB) * 128;
    const int bn = (wgid % NB) * 128;

    __shared__ u16 Alds[2][128 * 64];
    __shared__ u16 Blds[2][128 * 64];

    const int t    = threadIdx.x;
    const int lane = t & 63;
    const int wv   = t >> 6;
    const int wr   = wv >> 1;
    const int wc   = wv & 1;

    const int lrow = lane >> 3;
    const int lcol = (lane & 7) * 8;
    const int frow = lane & 15;
    const int fg   = lane >> 4;                // 0..3

    f32x4 acc[4][4];
    #pragma unroll
    for (int mi = 0; mi < 4; ++mi)
        #pragma unroll
        for (int ni = 0; ni < 4; ++ni) acc[mi][ni] = (f32x4)0.0f;

    auto STAGE = [&](int buf, int k0) {
        #pragma unroll
        for (int i = 0; i < 4; ++i) {
            const int c   = i * 4 + wv;
            const int row = c * 8 + lrow;
            __builtin_amdgcn_global_load_lds((gas_void*)(A + (size_t)(bm + row) * K + k0 + lcol),
                                             (las_void*)(&Alds[buf][c * 512]), 16, 0, 0);
            __builtin_amdgcn_global_load_lds((gas_void*)(W + (size_t)(bn + row) * K + k0 + lcol),
                                             (las_void*)(&Blds[buf][c * 512]), 16, 0, 0);
        }
    };

    STAGE(0, 0);
    __syncthreads();

    for (int ts = 0; ts < 6; ++ts) {
        if (ts < 5) STAGE((ts + 1) & 1, (ts + 1) * 64);
        const u16* Ab = Alds[ts & 1];
        const u16* Bb = Blds[ts & 1];
        #pragma unroll
        for (int ks = 0; ks < 2; ++ks) {
            const int sl = ks * 4 + fg;        // original slot
            bf16x8 af[4], bf[4];
            #pragma unroll
            for (int mi = 0; mi < 4; ++mi)
                af[mi] = *reinterpret_cast<const bf16x8*>(&Ab[frag_off(wr * 64 + mi * 16 + frow, sl)]);
            #pragma unroll
            for (int ni = 0; ni < 4; ++ni)
                bf[ni] = *reinterpret_cast<const bf16x8*>(&Bb[frag_off(wc * 64 + ni * 16 + frow, sl)]);
            #pragma unroll
            for (int mi = 0; mi < 4; ++mi)
                #pragma unroll
                for (int ni = 0; ni < 4; ++ni)
                    acc[mi][ni] = __builtin_amdgcn_mfma_f32_16x16x32_bf16(af[mi], bf[ni], acc[mi][ni], 0, 0, 0);
        }
        __syncthreads();
    }

    const int rbase = (lane >> 4) * 4;
    #pragma unroll
    for (int ni = 0; ni < 4; ++ni) {
        const int col = bn + wc * 64 + ni * 16 + frow;   // qkv channel
        const float bv = bias[col];
        const int h = col / 192;
        const int r = col - h * 192;
        #pragma unroll
        for (int mi = 0; mi < 4; ++mi) {
            #pragma unroll
            for (int j = 0; j < 4; ++j) {
                const int row = bm + wr * 64 + mi * 16 + rbase + j;   // token index
                const int bb = row / TOK;
                const int n  = row - bb * TOK;
                const u16 val = f2bf(acc[mi][ni][j] + bv);
                if (r < 64) {
                    qkb[(size_t)(bb * NH + h) * 4096 + swz(n, r)] = val;
                } else {
                    vt[(size_t)(bb * NH + h) * 8192 + swz(r - 64, n)] = val;
                }
            }
        }
    }
}

// ---------------------------------------------------------------------------
// Proj GEMM: C[M,384] = A[M,1024] @ W[384,1024]^T + bias, fp32 out.
// 2-phase dbuf, T2-swizzled LDS (A and W pre-swizzled in global).
// ---------------------------------------------------------------------------
__global__ __launch_bounds__(256)
void gemm_bf16_nt(const u16* __restrict__ A, const u16* __restrict__ W,
                  const float* __restrict__ bias, float* __restrict__ C,
                  int M, int N, int K)
{
    const int NB = N / 128;
    const int nwg = (M / 128) * NB;
    const int wgid = xcd_chunk(blockIdx.x, nwg);
    const int bm = (wgid / NB) * 128;
    const int bn = (wgid % NB) * 128;

    __shared__ u16 Alds[2][128 * 64];
    __shared__ u16 Blds[2][128 * 64];

    const int t    = threadIdx.x;
    const int lane = t & 63;
    const int wv   = t >> 6;
    const int wr   = wv >> 1;
    const int wc   = wv & 1;

    const int lrow = lane >> 3;
    const int lcol = (lane & 7) * 8;
    const int frow = lane & 15;
    const int fg   = lane >> 4;

    f32x4 acc[4][4];
    #pragma unroll
    for (int mi = 0; mi < 4; ++mi)
        #pragma unroll
        for (int ni = 0; ni < 4; ++ni) acc[mi][ni] = (f32x4)0.0f;

    auto STAGE = [&](int buf, int k0) {
        #pragma unroll
        for (int i = 0; i < 4; ++i) {
            const int c   = i * 4 + wv;
            const int row = c * 8 + lrow;
            __builtin_amdgcn_global_load_lds((gas_void*)(A + (size_t)(bm + row) * K + k0 + lcol),
                                             (las_void*)(&Alds[buf][c * 512]), 16, 0, 0);
            __builtin_amdgcn_global_load_lds((gas_void*)(W + (size_t)(bn + row) * K + k0 + lcol),
                                             (las_void*)(&Blds[buf][c * 512]), 16, 0, 0);
        }
    };

    const int NT = K / 64;
    STAGE(0, 0);
    __syncthreads();

    for (int ts = 0; ts < NT; ++ts) {
        if (ts < NT - 1) STAGE((ts + 1) & 1, (ts + 1) * 64);
        const u16* Ab = Alds[ts & 1];
        const u16* Bb = Blds[ts & 1];
        #pragma unroll
        for (int ks = 0; ks < 2; ++ks) {
            const int sl = ks * 4 + fg;
            bf16x8 af[4], bf[4];
            #pragma unroll
            for (int mi = 0; mi < 4; ++mi)
                af[mi] = *reinterpret_cast<const bf16x8*>(&Ab[frag_off(wr * 64 + mi * 16 + frow, sl)]);
            #pragma unroll
            for (int ni = 0; ni < 4; ++ni)
                bf[ni] = *reinterpret_cast<const bf16x8*>(&Bb[frag_off(wc * 64 + ni * 16 + frow, sl)]);
            #pragma unroll
            for (int mi = 0; mi < 4; ++mi)
                #pragma unroll
                for (int ni = 0; ni < 4; ++ni)
                    acc[mi][ni] = __builtin_amdgcn_mfma_f32_16x16x32_bf16(af[mi], bf[ni], acc[mi][ni], 0, 0, 0);
        }
        __syncthreads();
    }

    const int rbase = (lane >> 4) * 4;
    #pragma unroll
    for (int ni = 0; ni < 4; ++ni) {
        const int col = bn + wc * 64 + ni * 16 + frow;
        const float bv = bias[col];
        #pragma unroll
        for (int mi = 0; mi < 4; ++mi) {
            #pragma unroll
            for (int j = 0; j < 4; ++j) {
                const int row = bm + wr * 64 + mi * 16 + rbase + j;
                C[(size_t)row * N + col] = acc[mi][ni][j] + bv;
            }
        }
    }
}

// ---------------------------------------------------------------------------
// MFMA attention (validated r5/r7/r8). One block per (b,h), 256 thr / 4 waves.
// Only change: ab stores are pre-swizzled (T2) for the proj GEMM's A staging.
// ---------------------------------------------------------------------------
__global__ __launch_bounds__(256)
void attn_mfma(const u16* __restrict__ qkb, const u16* __restrict__ vt,
               const float* __restrict__ bias_full,   // [NH][49*49]
               u16* __restrict__ ab)                  // [Mc][1024] pre-swz
{
    __shared__ __align__(16) u16  QKs[64 * 64];
    __shared__ __align__(16) u16  Vts[128 * 64];
    __shared__ __align__(16) float S[64 * 80];
    __shared__ __align__(16) u16  Ps[64 * 64];

    const int t    = threadIdx.x;
    const int lane = t & 63;
    const int w    = t >> 6;
    const int fr   = lane & 15;
    const int fg   = lane >> 4;
    const int b    = blockIdx.x;
    const int h    = blockIdx.y;
    const int bh   = b * NH + h;

    const u16* gq = qkb + (size_t)bh * 4096;
    const u16* gv = vt  + (size_t)bh * 8192;
    #pragma unroll
    for (int i = 0; i < 2; ++i)
        __builtin_amdgcn_global_load_lds((gas_void*)(gq + (i * 256 + t) * 8),
                                         (las_void*)(QKs + (i * 256 + w * 64) * 8), 16, 0, 0);
    #pragma unroll
    for (int i = 0; i < 4; ++i)
        __builtin_amdgcn_global_load_lds((gas_void*)(gv + (i * 256 + t) * 8),
                                         (las_void*)(Vts + (i * 256 + w * 64) * 8), 16, 0, 0);
    __syncthreads();

    bf16x8 qf = *reinterpret_cast<const bf16x8*>(&QKs[swz(16 * w + fr, fg * 8)]);
    f32x4 sacc[4];
    #pragma unroll
    for (int nj = 0; nj < 4; ++nj) {
        bf16x8 kf = *reinterpret_cast<const bf16x8*>(&QKs[swz(16 * nj + fr, 32 + fg * 8)]);
        sacc[nj] = __builtin_amdgcn_mfma_f32_16x16x32_bf16(qf, kf, (f32x4)0.0f, 0, 0, 0);
    }

    const float scale = 0.17677669529663687f;  // 32^-0.5
    const float* bh_bias = bias_full + h * (TOK * TOK);
    #pragma unroll
    for (int nj = 0; nj < 4; ++nj) {
        #pragma unroll
        for (int j = 0; j < 4; ++j) {
            const int row = 16 * w + fg * 4 + j;
            const int col = 16 * nj + fr;
            const int rn = row < TOK ? row : TOK - 1;
            const int cm = col < TOK ? col : TOK - 1;
            S[row * 80 + col] = sacc[nj][j] * scale + bh_bias[rn * TOK + cm];
        }
    }
    __syncthreads();

    {
        const int n = t >> 2, j = t & 3;
        const float* Sr = &S[n * 80];
        float v[16];
        #pragma unroll
        for (int e = 0; e < 8; ++e) v[e]     = Sr[8 * j + e];
        #pragma unroll
        for (int e = 0; e < 8; ++e) v[8 + e] = Sr[32 + 8 * j + e];

        float mx = -1e30f;
        #pragma unroll
        for (int e = 0; e < 8; ++e) mx = fmaxf(mx, v[e]);
        #pragma unroll
        for (int e = 0; e < 8; ++e)
            if (32 + 8 * j + e < TOK) mx = fmaxf(mx, v[8 + e]);
        mx = fmaxf(mx, __shfl_xor(mx, 1, 4));
        mx = fmaxf(mx, __shfl_xor(mx, 2, 4));

        float sum = 0.f;
        #pragma unroll
        for (int e = 0; e < 8; ++e) { v[e] = __expf(v[e] - mx); sum += v[e]; }
        #pragma unroll
        for (int e = 0; e < 8; ++e) {
            const float ev = (32 + 8 * j + e < TOK) ? __expf(v[8 + e] - mx) : 0.f;
            v[8 + e] = ev; sum += ev;
        }
        sum += __shfl_xor(sum, 1, 4);
        sum += __shfl_xor(sum, 2, 4);
        const float inv = 1.f / sum;

        uint4 o;
        o.x = f2bf(v[0] * inv)  | ((unsigned)f2bf(v[1] * inv)  << 16);
        o.y = f2bf(v[2] * inv)  | ((unsigned)f2bf(v[3] * inv)  << 16);
        o.z = f2bf(v[4] * inv)  | ((unsigned)f2bf(v[5] * inv)  << 16);
        o.w = f2bf(v[6] * inv)  | ((unsigned)f2bf(v[7] * inv)  << 16);
        *reinterpret_cast<uint4*>(&Ps[swz(n, 8 * j)]) = o;
        o.x = f2bf(v[8] * inv)  | ((unsigned)f2bf(v[9] * inv)  << 16);
        o.y = f2bf(v[10] * inv) | ((unsigned)f2bf(v[11] * inv) << 16);
        o.z = f2bf(v[12] * inv) | ((unsigned)f2bf(v[13] * inv) << 16);
        o.w = f2bf(v[14] * inv) | ((unsigned)f2bf(v[15] * inv) << 16);
        *reinterpret_cast<uint4*>(&Ps[swz(n, 32 + 8 * j)]) = o;
    }
    __syncthreads();

    f32x4 oacc[8];
    #pragma unroll
    for (int nj = 0; nj < 8; ++nj) oacc[nj] = (f32x4)0.0f;
    #pragma unroll
    for (int ks = 0; ks < 2; ++ks) {
        bf16x8 pf = *reinterpret_cast<const bf16x8*>(&Ps[swz(16 * w + fr, ks * 32 + fg * 8)]);
        #pragma unroll
        for (int nj = 0; nj < 8; ++nj) {
            bf16x8 vf = *reinterpret_cast<const bf16x8*>(&Vts[swz(16 * nj + fr, ks * 32 + fg * 8)]);
            oacc[nj] = __builtin_amdgcn_mfma_f32_16x16x32_bf16(pf, vf, oacc[nj], 0, 0, 0);
        }
    }

    // Store O pre-swizzled (T2) for proj-A: 16B slot ^= (global row & 7).
    #pragma unroll
    for (int nj = 0; nj < 8; ++nj) {
        const int d = 16 * nj + fr;                       // 0..127 within head
        const int c = h * DHEAD + d;                      // 0..1023
        const int tp = c >> 6, sl = (c >> 3) & 7, cc = c & 7;
        #pragma unroll
        for (int j = 0; j < 4; ++j) {
            const int n = 16 * w + fg * 4 + j;
            if (n < TOK) {
                const int gr = b * TOK + n;
                ab[(size_t)gr * DHTOT + (tp << 6) + (((sl ^ (gr & 7)) << 3) | cc)] = f2bf(oacc[nj][j]);
            }
        }
    }
}

// ---------------------------------------------------------------------------
extern "C" void kernel_launch(void* const* d_in, const int* in_sizes, int n_in,
                              void* d_out, int out_size, void* d_ws, size_t ws_size,
                              hipStream_t stream)
{
    const float* x         = (const float*)d_in[0];
    const float* qkv_w     = (const float*)d_in[1];
    const float* qkv_b     = (const float*)d_in[2];
    const float* proj_w    = (const float*)d_in[3];
    const float* proj_b    = (const float*)d_in[4];
    const float* attn_bias = (const float*)d_in[5];
    const int*   bias_idxs = (const int*)d_in[6];

    const int Mtot  = in_sizes[0] / DIMM;            // 100352
    const int Btot  = Mtot / TOK;                    // 2048
    const int n_off = in_sizes[5] / NH;              // 49

    const size_t nWq = (size_t)HQKV * DIMM;
    const size_t nWp = (size_t)DIMM * DHTOT;
    float* bias_full = (float*)d_ws;                           // 76832 B
    u16*   wq        = (u16*)((char*)d_ws + 76832);
    u16*   wp        = wq + nWq;
    u16*   dyn       = wp + nWp;
    const size_t fixed_bytes = 76832 + (nWq + nWp) * sizeof(u16);
    const size_t per_batch = (size_t)TOK * DIMM * 2 + NH * 4096 * 2 + NH * 8192 * 2 + (size_t)TOK * DHTOT * 2;

    if (ws_size <= fixed_bytes) return;
    long BcL = (long)((ws_size - fixed_bytes) / per_batch);
    int Bc = (int)((BcL / 128) * 128);       // keep Mc multiple of 128
    if (Bc <= 0) return;
    if (Bc > Btot) Bc = Btot;                // round-3 evidence: single chunk in practice

    cast_swz<<<dim3(288), 256, 0, stream>>>(qkv_w, wq, DIMM / 8, (long)HQKV * (DIMM / 8));
    cast_swz<<<dim3(192), 256, 0, stream>>>(proj_w, wp, DHTOT / 8, (long)DIMM * (DHTOT / 8));
    bias_expand<<<dim3((NH * TOK * TOK + 255) / 256), 256, 0, stream>>>(attn_bias, bias_idxs, bias_full, n_off);

    for (int b0 = 0; b0 < Btot; b0 += Bc) {
        const int bc = (b0 + Bc <= Btot) ? Bc : (Btot - b0);   // multiple of 128
        const int Mc = bc * TOK;

        u16* xb  = dyn;
        u16* qkb = xb  + (size_t)Bc * TOK * DIMM;
        u16* vtb = qkb + (size_t)Bc * NH * 4096;
        u16* abb = vtb + (size_t)Bc * NH * 8192;

        const float* xc   = x + (size_t)b0 * TOK * DIMM;
        float*       outc = (float*)d_out + (size_t)b0 * TOK * DIMM;

        cast_swz<<<dim3(2048), 256, 0, stream>>>(xc, xb, DIMM / 8, (long)Mc * (DIMM / 8));

        gemm_qkv<<<dim3((Mc / 128) * (HQKV / 128)), 256, 0, stream>>>(xb, wq, qkv_b, qkb, vtb, Mc);

        attn_mfma<<<dim3(bc, NH), 256, 0, stream>>>(qkb, vtb, bias_full, abb);

        gemm_bf16_nt<<<dim3((Mc / 128) * (DIMM / 128)), 256, 0, stream>>>(abb, wp, proj_b, outc, Mc, DIMM, DHTOT);
    }
}

// Round 11
// 716.727 us; speedup vs baseline: 3.7735x; 1.0583x over previous
//
#include <hip/hip_runtime.h>
#include <cstddef>
#include <cstdint>

#define TOK    49      // tokens (7x7)
#define KD     32      // key dim
#define NH     8       // heads
#define DHEAD  128     // v head dim
#define HQKV   1536    // qkv channels
#define DHTOT  1024    // NH*DHEAD
#define DIMM   384     // model dim

typedef unsigned short u16;
typedef float  f32x4  __attribute__((ext_vector_type(4)));
typedef __bf16 bf16x8 __attribute__((ext_vector_type(8)));

typedef const __attribute__((address_space(1))) void gas_void;
typedef __attribute__((address_space(3))) void las_void;

static __device__ __forceinline__ u16 f2bf(float f) {
    unsigned int u = __builtin_bit_cast(unsigned int, f);
    return (u16)((u + 0x7fffu + ((u >> 16) & 1u)) >> 16);   // RNE
}

// XOR-swizzled index into a row-major [*][64] bf16 LDS image: 16B slots,
// slot ^= (row&7).
static __device__ __forceinline__ int swz(int row, int c) {
    return (row << 6) + ((((c >> 3) ^ (row & 7)) << 3) | (c & 7));
}

// Bijective XCD-chunked remap (m204).
static __device__ __forceinline__ int xcd_chunk(int bid, int nwg) {
    const int xcd = bid & 7, slot = bid >> 3;
    const int q = nwg >> 3, r = nwg & 7;
    return (xcd < r ? xcd * (q + 1) : r * (q + 1) + (xcd - r) * q) + slot;
}

// ---------------------------------------------------------------------------
// fp32 -> bf16 cast with T2 pre-swizzle (validated r10): within each 64-col
// panel, 16B slot s of row r stored at s^(r&7). K8 = K/8.
// ---------------------------------------------------------------------------
__global__ __launch_bounds__(256)
void cast_swz(const float* __restrict__ in, u16* __restrict__ out, int K8, long nchunk)
{
    long i = (long)blockIdx.x * 256 + threadIdx.x;
    const long stride = (long)gridDim.x * 256;
    for (; i < nchunk; i += stride) {
        const long row = i / K8;
        const int  c8  = (int)(i - row * K8);
        const int  slot = c8 & 7, tpan = c8 >> 3;
        float4 v0 = reinterpret_cast<const float4*>(in)[i * 2];
        float4 v1 = reinterpret_cast<const float4*>(in)[i * 2 + 1];
        uint4 o;
        o.x = f2bf(v0.x) | ((unsigned)f2bf(v0.y) << 16);
        o.y = f2bf(v0.z) | ((unsigned)f2bf(v0.w) << 16);
        o.z = f2bf(v1.x) | ((unsigned)f2bf(v1.y) << 16);
        o.w = f2bf(v1.z) | ((unsigned)f2bf(v1.w) << 16);
        *reinterpret_cast<uint4*>(out + row * (long)K8 * 8 + tpan * 64 +
                                  ((slot ^ ((int)row & 7)) << 3)) = o;
    }
}

// ---------------------------------------------------------------------------
// bias_full[h][n*49+m] = attn_bias[h][bias_idxs[n*49+m]]
// ---------------------------------------------------------------------------
__global__ __launch_bounds__(256)
void bias_expand(const float* __restrict__ attn_bias, const int* __restrict__ idxs,
                 float* __restrict__ bias_full, int n_off)
{
    int i = blockIdx.x * 256 + threadIdx.x;
    if (i < NH * TOK * TOK) {
        int h = i / (TOK * TOK), s = i - h * (TOK * TOK);
        bias_full[i] = attn_bias[h * n_off + idxs[s]];
    }
}

// Fragment read offset in a [rows][64]-short LDS tile with pre-swizzled
// content (validated r10).
static __device__ __forceinline__ int frag_off(int row, int ks8fg) {
    return (row << 6) + (((ks8fg ^ (row & 7)) << 3));
}

// ---------------------------------------------------------------------------
// QKV GEMM: [M,384] @ [1536,384]^T + bias -> PLAIN row-major bf16 [M][1536].
// K-loop/staging/T2 frag reads identical to r10; epilogue is the r4-proven
// plain store (no transpose scatter -- that moved to attn's LDS writes).
// ---------------------------------------------------------------------------
__global__ __launch_bounds__(256)
void gemm_qkv(const u16* __restrict__ A,      // [M][384] bf16 pre-swz
              const u16* __restrict__ W,      // [1536][384] bf16 pre-swz
              const float* __restrict__ bias, // [1536]
              u16* __restrict__ qkvb, int M)
{
    const int K = DIMM;                        // 384 -> 6 K-steps
    const int NB = HQKV / 128;                 // 12
    const int nwg = (M / 128) * NB;
    const int wgid = xcd_chunk(blockIdx.x, nwg);
    const int bm = (wgid / NB) * 128;
    const int bn = (wgid % NB) * 128;

    __shared__ u16 Alds[2][128 * 64];
    __shared__ u16 Blds[2][128 * 64];

    const int t    = threadIdx.x;
    const int lane = t & 63;
    const int wv   = t >> 6;
    const int wr   = wv >> 1;
    const int wc   = wv & 1;

    const int lrow = lane >> 3;
    const int lcol = (lane & 7) * 8;
    const int frow = lane & 15;
    const int fg   = lane >> 4;                // 0..3

    f32x4 acc[4][4];
    #pragma unroll
    for (int mi = 0; mi < 4; ++mi)
        #pragma unroll
        for (int ni = 0; ni < 4; ++ni) acc[mi][ni] = (f32x4)0.0f;

    auto STAGE = [&](int buf, int k0) {
        #pragma unroll
        for (int i = 0; i < 4; ++i) {
            const int c   = i * 4 + wv;
            const int row = c * 8 + lrow;
            __builtin_amdgcn_global_load_lds((gas_void*)(A + (size_t)(bm + row) * K + k0 + lcol),
                                             (las_void*)(&Alds[buf][c * 512]), 16, 0, 0);
            __builtin_amdgcn_global_load_lds((gas_void*)(W + (size_t)(bn + row) * K + k0 + lcol),
                                             (las_void*)(&Blds[buf][c * 512]), 16, 0, 0);
        }
    };

    STAGE(0, 0);
    __syncthreads();

    for (int ts = 0; ts < 6; ++ts) {
        if (ts < 5) STAGE((ts + 1) & 1, (ts + 1) * 64);
        const u16* Ab = Alds[ts & 1];
        const u16* Bb = Blds[ts & 1];
        #pragma unroll
        for (int ks = 0; ks < 2; ++ks) {
            const int sl = ks * 4 + fg;        // original slot
            bf16x8 af[4], bf[4];
            #pragma unroll
            for (int mi = 0; mi < 4; ++mi)
                af[mi] = *reinterpret_cast<const bf16x8*>(&Ab[frag_off(wr * 64 + mi * 16 + frow, sl)]);
            #pragma unroll
            for (int ni = 0; ni < 4; ++ni)
                bf[ni] = *reinterpret_cast<const bf16x8*>(&Bb[frag_off(wc * 64 + ni * 16 + frow, sl)]);
            #pragma unroll
            for (int mi = 0; mi < 4; ++mi)
                #pragma unroll
                for (int ni = 0; ni < 4; ++ni)
                    acc[mi][ni] = __builtin_amdgcn_mfma_f32_16x16x32_bf16(af[mi], bf[ni], acc[mi][ni], 0, 0, 0);
        }
        __syncthreads();
    }

    // Plain row-major epilogue (r4-proven shape).
    const int rbase = (lane >> 4) * 4;
    #pragma unroll
    for (int ni = 0; ni < 4; ++ni) {
        const int col = bn + wc * 64 + ni * 16 + frow;
        const float bv = bias[col];
        #pragma unroll
        for (int mi = 0; mi < 4; ++mi) {
            #pragma unroll
            for (int j = 0; j < 4; ++j) {
                const int row = bm + wr * 64 + mi * 16 + rbase + j;
                qkvb[(size_t)row * HQKV + col] = f2bf(acc[mi][ni][j] + bv);
            }
        }
    }
}

// ---------------------------------------------------------------------------
// Proj GEMM (validated r10): C[M,384] = A[M,1024] @ W[384,1024]^T + bias.
// ---------------------------------------------------------------------------
__global__ __launch_bounds__(256)
void gemm_bf16_nt(const u16* __restrict__ A, const u16* __restrict__ W,
                  const float* __restrict__ bias, float* __restrict__ C,
                  int M, int N, int K)
{
    const int NB = N / 128;
    const int nwg = (M / 128) * NB;
    const int wgid = xcd_chunk(blockIdx.x, nwg);
    const int bm = (wgid / NB) * 128;
    const int bn = (wgid % NB) * 128;

    __shared__ u16 Alds[2][128 * 64];
    __shared__ u16 Blds[2][128 * 64];

    const int t    = threadIdx.x;
    const int lane = t & 63;
    const int wv   = t >> 6;
    const int wr   = wv >> 1;
    const int wc   = wv & 1;

    const int lrow = lane >> 3;
    const int lcol = (lane & 7) * 8;
    const int frow = lane & 15;
    const int fg   = lane >> 4;

    f32x4 acc[4][4];
    #pragma unroll
    for (int mi = 0; mi < 4; ++mi)
        #pragma unroll
        for (int ni = 0; ni < 4; ++ni) acc[mi][ni] = (f32x4)0.0f;

    auto STAGE = [&](int buf, int k0) {
        #pragma unroll
        for (int i = 0; i < 4; ++i) {
            const int c   = i * 4 + wv;
            const int row = c * 8 + lrow;
            __builtin_amdgcn_global_load_lds((gas_void*)(A + (size_t)(bm + row) * K + k0 + lcol),
                                             (las_void*)(&Alds[buf][c * 512]), 16, 0, 0);
            __builtin_amdgcn_global_load_lds((gas_void*)(W + (size_t)(bn + row) * K + k0 + lcol),
                                             (las_void*)(&Blds[buf][c * 512]), 16, 0, 0);
        }
    };

    const int NT = K / 64;
    STAGE(0, 0);
    __syncthreads();

    for (int ts = 0; ts < NT; ++ts) {
        if (ts < NT - 1) STAGE((ts + 1) & 1, (ts + 1) * 64);
        const u16* Ab = Alds[ts & 1];
        const u16* Bb = Blds[ts & 1];
        #pragma unroll
        for (int ks = 0; ks < 2; ++ks) {
            const int sl = ks * 4 + fg;
            bf16x8 af[4], bf[4];
            #pragma unroll
            for (int mi = 0; mi < 4; ++mi)
                af[mi] = *reinterpret_cast<const bf16x8*>(&Ab[frag_off(wr * 64 + mi * 16 + frow, sl)]);
            #pragma unroll
            for (int ni = 0; ni < 4; ++ni)
                bf[ni] = *reinterpret_cast<const bf16x8*>(&Bb[frag_off(wc * 64 + ni * 16 + frow, sl)]);
            #pragma unroll
            for (int mi = 0; mi < 4; ++mi)
                #pragma unroll
                for (int ni = 0; ni < 4; ++ni)
                    acc[mi][ni] = __builtin_amdgcn_mfma_f32_16x16x32_bf16(af[mi], bf[ni], acc[mi][ni], 0, 0, 0);
        }
        __syncthreads();
    }

    const int rbase = (lane >> 4) * 4;
    #pragma unroll
    for (int ni = 0; ni < 4; ++ni) {
        const int col = bn + wc * 64 + ni * 16 + frow;
        const float bv = bias[col];
        #pragma unroll
        for (int mi = 0; mi < 4; ++mi) {
            #pragma unroll
            for (int j = 0; j < 4; ++j) {
                const int row = bm + wr * 64 + mi * 16 + rbase + j;
                C[(size_t)row * N + col] = acc[mi][ni][j] + bv;
            }
        }
    }
}

// ---------------------------------------------------------------------------
// MFMA attention. One block per (b,h), 256 thr / 4 waves.
// NEW staging: coalesced 16B register gather from plain qkvb[M][1536] +
// LDS writes (q/k: swizzled ds_write_b128; v: 8x ds_write_b16 transpose
// scatter -- LDS-side, cheap). V pad cols 49..63 zero-filled (LDS garbage
// could be inf/NaN; 0 * garbage would poison PV). Core math = r10.
// ---------------------------------------------------------------------------
__global__ __launch_bounds__(256)
void attn_mfma(const u16* __restrict__ qkvb,          // [Mc][1536] bf16
               const float* __restrict__ bias_full,   // [NH][49*49]
               u16* __restrict__ ab)                  // [Mc][1024] pre-swz
{
    __shared__ __align__(16) u16  QKs[64 * 64];
    __shared__ __align__(16) u16  Vts[128 * 64];
    __shared__ __align__(16) float S[64 * 80];
    __shared__ __align__(16) u16  Ps[64 * 64];

    const int t    = threadIdx.x;
    const int lane = t & 63;
    const int w    = t >> 6;
    const int fr   = lane & 15;
    const int fg   = lane >> 4;
    const int b    = blockIdx.x;
    const int h    = blockIdx.y;

    // ---- phase 0: zero V pad (cols 48..63 = slots 6,7 of every row) ----
    if (t < 128 * 2) {
        const int row = t >> 1, sl = 6 + (t & 1);
        *reinterpret_cast<uint4*>(&Vts[(row << 6) + ((sl ^ (row & 7)) << 3)]) =
            make_uint4(0, 0, 0, 0);
    }
    __syncthreads();

    // ---- phase 1: gather (b,h) slice, write LDS ----
    const u16* qrow = qkvb + (size_t)b * TOK * HQKV + h * 192;
    for (int flat = t; flat < TOK * 24; flat += 256) {
        const int n = flat / 24, c24 = flat - n * 24;
        uint4 u = *reinterpret_cast<const uint4*>(qrow + (size_t)n * HQKV + c24 * 8);
        if (c24 < 8) {
            // q/k: one swizzled 16B slot of QKs row n
            *reinterpret_cast<uint4*>(&QKs[(n << 6) + ((c24 ^ (n & 7)) << 3)]) = u;
        } else {
            // v: 8 consecutive d at token n -> Vts rows d0..d0+7, col n
            const int d0 = (c24 - 8) * 8;
            u16 vals[8];
            *reinterpret_cast<uint4*>(vals) = u;
            #pragma unroll
            for (int e = 0; e < 8; ++e)
                Vts[swz(d0 + e, n)] = vals[e];
        }
    }
    __syncthreads();

    bf16x8 qf = *reinterpret_cast<const bf16x8*>(&QKs[swz(16 * w + fr, fg * 8)]);
    f32x4 sacc[4];
    #pragma unroll
    for (int nj = 0; nj < 4; ++nj) {
        bf16x8 kf = *reinterpret_cast<const bf16x8*>(&QKs[swz(16 * nj + fr, 32 + fg * 8)]);
        sacc[nj] = __builtin_amdgcn_mfma_f32_16x16x32_bf16(qf, kf, (f32x4)0.0f, 0, 0, 0);
    }

    const float scale = 0.17677669529663687f;  // 32^-0.5
    const float* bh_bias = bias_full + h * (TOK * TOK);
    #pragma unroll
    for (int nj = 0; nj < 4; ++nj) {
        #pragma unroll
        for (int j = 0; j < 4; ++j) {
            const int row = 16 * w + fg * 4 + j;
            const int col = 16 * nj + fr;
            const int rn = row < TOK ? row : TOK - 1;
            const int cm = col < TOK ? col : TOK - 1;
            S[row * 80 + col] = sacc[nj][j] * scale + bh_bias[rn * TOK + cm];
        }
    }
    __syncthreads();

    {
        const int n = t >> 2, j = t & 3;
        const float* Sr = &S[n * 80];
        float v[16];
        #pragma unroll
        for (int e = 0; e < 8; ++e) v[e]     = Sr[8 * j + e];
        #pragma unroll
        for (int e = 0; e < 8; ++e) v[8 + e] = Sr[32 + 8 * j + e];

        float mx = -1e30f;
        #pragma unroll
        for (int e = 0; e < 8; ++e) mx = fmaxf(mx, v[e]);
        #pragma unroll
        for (int e = 0; e < 8; ++e)
            if (32 + 8 * j + e < TOK) mx = fmaxf(mx, v[8 + e]);
        mx = fmaxf(mx, __shfl_xor(mx, 1, 4));
        mx = fmaxf(mx, __shfl_xor(mx, 2, 4));

        float sum = 0.f;
        #pragma unroll
        for (int e = 0; e < 8; ++e) { v[e] = __expf(v[e] - mx); sum += v[e]; }
        #pragma unroll
        for (int e = 0; e < 8; ++e) {
            const float ev = (32 + 8 * j + e < TOK) ? __expf(v[8 + e] - mx) : 0.f;
            v[8 + e] = ev; sum += ev;
        }
        sum += __shfl_xor(sum, 1, 4);
        sum += __shfl_xor(sum, 2, 4);
        const float inv = 1.f / sum;

        uint4 o;
        o.x = f2bf(v[0] * inv)  | ((unsigned)f2bf(v[1] * inv)  << 16);
        o.y = f2bf(v[2] * inv)  | ((unsigned)f2bf(v[3] * inv)  << 16);
        o.z = f2bf(v[4] * inv)  | ((unsigned)f2bf(v[5] * inv)  << 16);
        o.w = f2bf(v[6] * inv)  | ((unsigned)f2bf(v[7] * inv)  << 16);
        *reinterpret_cast<uint4*>(&Ps[swz(n, 8 * j)]) = o;
        o.x = f2bf(v[8] * inv)  | ((unsigned)f2bf(v[9] * inv)  << 16);
        o.y = f2bf(v[10] * inv) | ((unsigned)f2bf(v[11] * inv) << 16);
        o.z = f2bf(v[12] * inv) | ((unsigned)f2bf(v[13] * inv) << 16);
        o.w = f2bf(v[14] * inv) | ((unsigned)f2bf(v[15] * inv) << 16);
        *reinterpret_cast<uint4*>(&Ps[swz(n, 32 + 8 * j)]) = o;
    }
    __syncthreads();

    f32x4 oacc[8];
    #pragma unroll
    for (int nj = 0; nj < 8; ++nj) oacc[nj] = (f32x4)0.0f;
    #pragma unroll
    for (int ks = 0; ks < 2; ++ks) {
        bf16x8 pf = *reinterpret_cast<const bf16x8*>(&Ps[swz(16 * w + fr, ks * 32 + fg * 8)]);
        #pragma unroll
        for (int nj = 0; nj < 8; ++nj) {
            bf16x8 vf = *reinterpret_cast<const bf16x8*>(&Vts[swz(16 * nj + fr, ks * 32 + fg * 8)]);
            oacc[nj] = __builtin_amdgcn_mfma_f32_16x16x32_bf16(pf, vf, oacc[nj], 0, 0, 0);
        }
    }

    // Store O pre-swizzled (T2) for proj-A (validated r10).
    #pragma unroll
    for (int nj = 0; nj < 8; ++nj) {
        const int d = 16 * nj + fr;
        const int c = h * DHEAD + d;
        const int tp = c >> 6, sl = (c >> 3) & 7, cc = c & 7;
        #pragma unroll
        for (int j = 0; j < 4; ++j) {
            const int n = 16 * w + fg * 4 + j;
            if (n < TOK) {
                const int gr = b * TOK + n;
                ab[(size_t)gr * DHTOT + (tp << 6) + (((sl ^ (gr & 7)) << 3) | cc)] = f2bf(oacc[nj][j]);
            }
        }
    }
}

// ---------------------------------------------------------------------------
extern "C" void kernel_launch(void* const* d_in, const int* in_sizes, int n_in,
                              void* d_out, int out_size, void* d_ws, size_t ws_size,
                              hipStream_t stream)
{
    const float* x         = (const float*)d_in[0];
    const float* qkv_w     = (const float*)d_in[1];
    const float* qkv_b     = (const float*)d_in[2];
    const float* proj_w    = (const float*)d_in[3];
    const float* proj_b    = (const float*)d_in[4];
    const float* attn_bias = (const float*)d_in[5];
    const int*   bias_idxs = (const int*)d_in[6];

    const int Mtot  = in_sizes[0] / DIMM;            // 100352
    const int Btot  = Mtot / TOK;                    // 2048
    const int n_off = in_sizes[5] / NH;              // 49

    const size_t nWq = (size_t)HQKV * DIMM;
    const size_t nWp = (size_t)DIMM * DHTOT;
    float* bias_full = (float*)d_ws;                           // 76832 B
    u16*   wq        = (u16*)((char*)d_ws + 76832);
    u16*   wp        = wq + nWq;
    u16*   dyn       = wp + nWp;
    const size_t fixed_bytes = 76832 + (nWq + nWp) * sizeof(u16);
    // per-batch: xb 49*384*2 + qkvb 49*1536*2 + ab 49*1024*2
    const size_t per_batch = (size_t)TOK * (DIMM + HQKV + DHTOT) * 2;

    if (ws_size <= fixed_bytes) return;
    long BcL = (long)((ws_size - fixed_bytes) / per_batch);
    int Bc = (int)((BcL / 128) * 128);       // keep Mc multiple of 128
    if (Bc <= 0) return;
    if (Bc > Btot) Bc = Btot;                // round-3 evidence: single chunk in practice

    cast_swz<<<dim3(288), 256, 0, stream>>>(qkv_w, wq, DIMM / 8, (long)HQKV * (DIMM / 8));
    cast_swz<<<dim3(192), 256, 0, stream>>>(proj_w, wp, DHTOT / 8, (long)DIMM * (DHTOT / 8));
    bias_expand<<<dim3((NH * TOK * TOK + 255) / 256), 256, 0, stream>>>(attn_bias, bias_idxs, bias_full, n_off);

    for (int b0 = 0; b0 < Btot; b0 += Bc) {
        const int bc = (b0 + Bc <= Btot) ? Bc : (Btot - b0);   // multiple of 128
        const int Mc = bc * TOK;

        u16* xb   = dyn;
        u16* qkvb = xb   + (size_t)Bc * TOK * DIMM;
        u16* abb  = qkvb + (size_t)Bc * TOK * HQKV;

        const float* xc   = x + (size_t)b0 * TOK * DIMM;
        float*       outc = (float*)d_out + (size_t)b0 * TOK * DIMM;

        cast_swz<<<dim3(2048), 256, 0, stream>>>(xc, xb, DIMM / 8, (long)Mc * (DIMM / 8));

        gemm_qkv<<<dim3((Mc / 128) * (HQKV / 128)), 256, 0, stream>>>(xb, wq, qkv_b, qkvb, Mc);

        attn_mfma<<<dim3(bc, NH), 256, 0, stream>>>(qkvb, bias_full, abb);

        gemm_bf16_nt<<<dim3((Mc / 128) * (DIMM / 128)), 256, 0, stream>>>(abb, wp, proj_b, outc, Mc, DIMM, DHTOT);
    }
}

// Round 12
// 709.511 us; speedup vs baseline: 3.8119x; 1.0102x over previous
//
#include <hip/hip_runtime.h>
#include <cstddef>
#include <cstdint>

#define TOK    49      // tokens (7x7)
#define KD     32      // key dim
#define NH     8       // heads
#define DHEAD  128     // v head dim
#define HQKV   1536    // qkv channels
#define DHTOT  1024    // NH*DHEAD
#define DIMM   384     // model dim

typedef unsigned short u16;
typedef float  f32x4  __attribute__((ext_vector_type(4)));
typedef __bf16 bf16x8 __attribute__((ext_vector_type(8)));

typedef const __attribute__((address_space(1))) void gas_void;
typedef __attribute__((address_space(3))) void las_void;

static __device__ __forceinline__ u16 f2bf(float f) {
    unsigned int u = __builtin_bit_cast(unsigned int, f);
    return (u16)((u + 0x7fffu + ((u >> 16) & 1u)) >> 16);   // RNE
}

// XOR-swizzled index into a row-major [*][64] bf16 LDS image: 16B slots,
// slot ^= (row&7).
static __device__ __forceinline__ int swz(int row, int c) {
    return (row << 6) + ((((c >> 3) ^ (row & 7)) << 3) | (c & 7));
}

// Bijective XCD-chunked remap (m204).
static __device__ __forceinline__ int xcd_chunk(int bid, int nwg) {
    const int xcd = bid & 7, slot = bid >> 3;
    const int q = nwg >> 3, r = nwg & 7;
    return (xcd < r ? xcd * (q + 1) : r * (q + 1) + (xcd - r) * q) + slot;
}

// T4 primitives: raw barrier + counted vmcnt (never 0 inside K-loop).
#define BAR() __builtin_amdgcn_s_barrier()
#define WAIT_VM8() asm volatile("s_waitcnt vmcnt(8)" ::: "memory")
#define WAIT_VM0() asm volatile("s_waitcnt vmcnt(0)" ::: "memory")

// ---------------------------------------------------------------------------
// fp32 -> bf16 cast with T2 pre-swizzle (validated r10/r11).
// ---------------------------------------------------------------------------
__global__ __launch_bounds__(256)
void cast_swz(const float* __restrict__ in, u16* __restrict__ out, int K8, long nchunk)
{
    long i = (long)blockIdx.x * 256 + threadIdx.x;
    const long stride = (long)gridDim.x * 256;
    for (; i < nchunk; i += stride) {
        const long row = i / K8;
        const int  c8  = (int)(i - row * K8);
        const int  slot = c8 & 7, tpan = c8 >> 3;
        float4 v0 = reinterpret_cast<const float4*>(in)[i * 2];
        float4 v1 = reinterpret_cast<const float4*>(in)[i * 2 + 1];
        uint4 o;
        o.x = f2bf(v0.x) | ((unsigned)f2bf(v0.y) << 16);
        o.y = f2bf(v0.z) | ((unsigned)f2bf(v0.w) << 16);
        o.z = f2bf(v1.x) | ((unsigned)f2bf(v1.y) << 16);
        o.w = f2bf(v1.z) | ((unsigned)f2bf(v1.w) << 16);
        *reinterpret_cast<uint4*>(out + row * (long)K8 * 8 + tpan * 64 +
                                  ((slot ^ ((int)row & 7)) << 3)) = o;
    }
}

// ---------------------------------------------------------------------------
// bias_full[h][n*49+m] = attn_bias[h][bias_idxs[n*49+m]]
// ---------------------------------------------------------------------------
__global__ __launch_bounds__(256)
void bias_expand(const float* __restrict__ attn_bias, const int* __restrict__ idxs,
                 float* __restrict__ bias_full, int n_off)
{
    int i = blockIdx.x * 256 + threadIdx.x;
    if (i < NH * TOK * TOK) {
        int h = i / (TOK * TOK), s = i - h * (TOK * TOK);
        bias_full[i] = attn_bias[h * n_off + idxs[s]];
    }
}

// Fragment read offset in a [rows][64]-short LDS tile with pre-swizzled
// content (validated r10).
static __device__ __forceinline__ int frag_off(int row, int ks8fg) {
    return (row << 6) + (((ks8fg ^ (row & 7)) << 3));
}

// ---------------------------------------------------------------------------
// QKV GEMM: [M,384] @ [1536,384]^T + bias -> plain row-major bf16 [M][1536].
// T4 K-loop: 2-deep prefetch, counted vmcnt(8), raw barriers (no drain).
// ---------------------------------------------------------------------------
__global__ __launch_bounds__(256)
void gemm_qkv(const u16* __restrict__ A,      // [M][384] bf16 pre-swz
              const u16* __restrict__ W,      // [1536][384] bf16 pre-swz
              const float* __restrict__ bias, // [1536]
              u16* __restrict__ qkvb, int M)
{
    const int K = DIMM;                        // 384 -> 6 K-steps
    const int NB = HQKV / 128;                 // 12
    const int nwg = (M / 128) * NB;
    const int wgid = xcd_chunk(blockIdx.x, nwg);
    const int bm = (wgid / NB) * 128;
    const int bn = (wgid % NB) * 128;

    __shared__ u16 Alds[2][128 * 64];
    __shared__ u16 Blds[2][128 * 64];

    const int t    = threadIdx.x;
    const int lane = t & 63;
    const int wv   = t >> 6;
    const int wr   = wv >> 1;
    const int wc   = wv & 1;

    const int lrow = lane >> 3;
    const int lcol = (lane & 7) * 8;
    const int frow = lane & 15;
    const int fg   = lane >> 4;                // 0..3

    f32x4 acc[4][4];
    #pragma unroll
    for (int mi = 0; mi < 4; ++mi)
        #pragma unroll
        for (int ni = 0; ni < 4; ++ni) acc[mi][ni] = (f32x4)0.0f;

    // Each wave issues exactly 8 global_load_lds per STAGE (4 A + 4 B).
    auto STAGE = [&](int buf, int k0) {
        #pragma unroll
        for (int i = 0; i < 4; ++i) {
            const int c   = i * 4 + wv;
            const int row = c * 8 + lrow;
            __builtin_amdgcn_global_load_lds((gas_void*)(A + (size_t)(bm + row) * K + k0 + lcol),
                                             (las_void*)(&Alds[buf][c * 512]), 16, 0, 0);
            __builtin_amdgcn_global_load_lds((gas_void*)(W + (size_t)(bn + row) * K + k0 + lcol),
                                             (las_void*)(&Blds[buf][c * 512]), 16, 0, 0);
        }
    };

    STAGE(0, 0);
    STAGE(1, 64);                              // 16 loads/wave in flight

    const int NT = 6;
    for (int ts = 0; ts < NT; ++ts) {
        if (ts < NT - 1) { WAIT_VM8(); }       // oldest stage landed; next still flying
        else             { WAIT_VM0(); }
        BAR();                                 // buf[ts&1] complete for ALL waves
        const u16* Ab = Alds[ts & 1];
        const u16* Bb = Blds[ts & 1];
        #pragma unroll
        for (int ks = 0; ks < 2; ++ks) {
            const int sl = ks * 4 + fg;        // original slot
            bf16x8 af[4], bf[4];
            #pragma unroll
            for (int mi = 0; mi < 4; ++mi)
                af[mi] = *reinterpret_cast<const bf16x8*>(&Ab[frag_off(wr * 64 + mi * 16 + frow, sl)]);
            #pragma unroll
            for (int ni = 0; ni < 4; ++ni)
                bf[ni] = *reinterpret_cast<const bf16x8*>(&Bb[frag_off(wc * 64 + ni * 16 + frow, sl)]);
            #pragma unroll
            for (int mi = 0; mi < 4; ++mi)
                #pragma unroll
                for (int ni = 0; ni < 4; ++ni)
                    acc[mi][ni] = __builtin_amdgcn_mfma_f32_16x16x32_bf16(af[mi], bf[ni], acc[mi][ni], 0, 0, 0);
        }
        BAR();                                 // all waves done reading buf[ts&1]
        if (ts < NT - 2) STAGE(ts & 1, (ts + 2) * 64);   // refill freed buffer
    }

    // Plain row-major epilogue (validated r11).
    const int rbase = (lane >> 4) * 4;
    #pragma unroll
    for (int ni = 0; ni < 4; ++ni) {
        const int col = bn + wc * 64 + ni * 16 + frow;
        const float bv = bias[col];
        #pragma unroll
        for (int mi = 0; mi < 4; ++mi) {
            #pragma unroll
            for (int j = 0; j < 4; ++j) {
                const int row = bm + wr * 64 + mi * 16 + rbase + j;
                qkvb[(size_t)row * HQKV + col] = f2bf(acc[mi][ni][j] + bv);
            }
        }
    }
}

// ---------------------------------------------------------------------------
// Proj GEMM: C[M,384] = A[M,1024] @ W[384,1024]^T + bias. Same T4 K-loop.
// ---------------------------------------------------------------------------
__global__ __launch_bounds__(256)
void gemm_bf16_nt(const u16* __restrict__ A, const u16* __restrict__ W,
                  const float* __restrict__ bias, float* __restrict__ C,
                  int M, int N, int K)
{
    const int NB = N / 128;
    const int nwg = (M / 128) * NB;
    const int wgid = xcd_chunk(blockIdx.x, nwg);
    const int bm = (wgid / NB) * 128;
    const int bn = (wgid % NB) * 128;

    __shared__ u16 Alds[2][128 * 64];
    __shared__ u16 Blds[2][128 * 64];

    const int t    = threadIdx.x;
    const int lane = t & 63;
    const int wv   = t >> 6;
    const int wr   = wv >> 1;
    const int wc   = wv & 1;

    const int lrow = lane >> 3;
    const int lcol = (lane & 7) * 8;
    const int frow = lane & 15;
    const int fg   = lane >> 4;

    f32x4 acc[4][4];
    #pragma unroll
    for (int mi = 0; mi < 4; ++mi)
        #pragma unroll
        for (int ni = 0; ni < 4; ++ni) acc[mi][ni] = (f32x4)0.0f;

    auto STAGE = [&](int buf, int k0) {
        #pragma unroll
        for (int i = 0; i < 4; ++i) {
            const int c   = i * 4 + wv;
            const int row = c * 8 + lrow;
            __builtin_amdgcn_global_load_lds((gas_void*)(A + (size_t)(bm + row) * K + k0 + lcol),
                                             (las_void*)(&Alds[buf][c * 512]), 16, 0, 0);
            __builtin_amdgcn_global_load_lds((gas_void*)(W + (size_t)(bn + row) * K + k0 + lcol),
                                             (las_void*)(&Blds[buf][c * 512]), 16, 0, 0);
        }
    };

    const int NT = K / 64;
    STAGE(0, 0);
    STAGE(1, 64);

    for (int ts = 0; ts < NT; ++ts) {
        if (ts < NT - 1) { WAIT_VM8(); }
        else             { WAIT_VM0(); }
        BAR();
        const u16* Ab = Alds[ts & 1];
        const u16* Bb = Blds[ts & 1];
        #pragma unroll
        for (int ks = 0; ks < 2; ++ks) {
            const int sl = ks * 4 + fg;
            bf16x8 af[4], bf[4];
            #pragma unroll
            for (int mi = 0; mi < 4; ++mi)
                af[mi] = *reinterpret_cast<const bf16x8*>(&Ab[frag_off(wr * 64 + mi * 16 + frow, sl)]);
            #pragma unroll
            for (int ni = 0; ni < 4; ++ni)
                bf[ni] = *reinterpret_cast<const bf16x8*>(&Bb[frag_off(wc * 64 + ni * 16 + frow, sl)]);
            #pragma unroll
            for (int mi = 0; mi < 4; ++mi)
                #pragma unroll
                for (int ni = 0; ni < 4; ++ni)
                    acc[mi][ni] = __builtin_amdgcn_mfma_f32_16x16x32_bf16(af[mi], bf[ni], acc[mi][ni], 0, 0, 0);
        }
        BAR();
        if (ts < NT - 2) STAGE(ts & 1, (ts + 2) * 64);
    }

    const int rbase = (lane >> 4) * 4;
    #pragma unroll
    for (int ni = 0; ni < 4; ++ni) {
        const int col = bn + wc * 64 + ni * 16 + frow;
        const float bv = bias[col];
        #pragma unroll
        for (int mi = 0; mi < 4; ++mi) {
            #pragma unroll
            for (int j = 0; j < 4; ++j) {
                const int row = bm + wr * 64 + mi * 16 + rbase + j;
                C[(size_t)row * N + col] = acc[mi][ni][j] + bv;
            }
        }
    }
}

// ---------------------------------------------------------------------------
// MFMA attention (validated r11). One block per (b,h), 256 thr / 4 waves.
// ---------------------------------------------------------------------------
__global__ __launch_bounds__(256)
void attn_mfma(const u16* __restrict__ qkvb,          // [Mc][1536] bf16
               const float* __restrict__ bias_full,   // [NH][49*49]
               u16* __restrict__ ab)                  // [Mc][1024] pre-swz
{
    __shared__ __align__(16) u16  QKs[64 * 64];
    __shared__ __align__(16) u16  Vts[128 * 64];
    __shared__ __align__(16) float S[64 * 80];
    __shared__ __align__(16) u16  Ps[64 * 64];

    const int t    = threadIdx.x;
    const int lane = t & 63;
    const int w    = t >> 6;
    const int fr   = lane & 15;
    const int fg   = lane >> 4;
    const int b    = blockIdx.x;
    const int h    = blockIdx.y;

    // ---- phase 0: zero V pad (cols 48..63 = slots 6,7 of every row) ----
    if (t < 128 * 2) {
        const int row = t >> 1, sl = 6 + (t & 1);
        *reinterpret_cast<uint4*>(&Vts[(row << 6) + ((sl ^ (row & 7)) << 3)]) =
            make_uint4(0, 0, 0, 0);
    }
    __syncthreads();

    // ---- phase 1: gather (b,h) slice, write LDS ----
    const u16* qrow = qkvb + (size_t)b * TOK * HQKV + h * 192;
    for (int flat = t; flat < TOK * 24; flat += 256) {
        const int n = flat / 24, c24 = flat - n * 24;
        uint4 u = *reinterpret_cast<const uint4*>(qrow + (size_t)n * HQKV + c24 * 8);
        if (c24 < 8) {
            *reinterpret_cast<uint4*>(&QKs[(n << 6) + ((c24 ^ (n & 7)) << 3)]) = u;
        } else {
            const int d0 = (c24 - 8) * 8;
            u16 vals[8];
            *reinterpret_cast<uint4*>(vals) = u;
            #pragma unroll
            for (int e = 0; e < 8; ++e)
                Vts[swz(d0 + e, n)] = vals[e];
        }
    }
    __syncthreads();

    bf16x8 qf = *reinterpret_cast<const bf16x8*>(&QKs[swz(16 * w + fr, fg * 8)]);
    f32x4 sacc[4];
    #pragma unroll
    for (int nj = 0; nj < 4; ++nj) {
        bf16x8 kf = *reinterpret_cast<const bf16x8*>(&QKs[swz(16 * nj + fr, 32 + fg * 8)]);
        sacc[nj] = __builtin_amdgcn_mfma_f32_16x16x32_bf16(qf, kf, (f32x4)0.0f, 0, 0, 0);
    }

    const float scale = 0.17677669529663687f;  // 32^-0.5
    const float* bh_bias = bias_full + h * (TOK * TOK);
    #pragma unroll
    for (int nj = 0; nj < 4; ++nj) {
        #pragma unroll
        for (int j = 0; j < 4; ++j) {
            const int row = 16 * w + fg * 4 + j;
            const int col = 16 * nj + fr;
            const int rn = row < TOK ? row : TOK - 1;
            const int cm = col < TOK ? col : TOK - 1;
            S[row * 80 + col] = sacc[nj][j] * scale + bh_bias[rn * TOK + cm];
        }
    }
    __syncthreads();

    {
        const int n = t >> 2, j = t & 3;
        const float* Sr = &S[n * 80];
        float v[16];
        #pragma unroll
        for (int e = 0; e < 8; ++e) v[e]     = Sr[8 * j + e];
        #pragma unroll
        for (int e = 0; e < 8; ++e) v[8 + e] = Sr[32 + 8 * j + e];

        float mx = -1e30f;
        #pragma unroll
        for (int e = 0; e < 8; ++e) mx = fmaxf(mx, v[e]);
        #pragma unroll
        for (int e = 0; e < 8; ++e)
            if (32 + 8 * j + e < TOK) mx = fmaxf(mx, v[8 + e]);
        mx = fmaxf(mx, __shfl_xor(mx, 1, 4));
        mx = fmaxf(mx, __shfl_xor(mx, 2, 4));

        float sum = 0.f;
        #pragma unroll
        for (int e = 0; e < 8; ++e) { v[e] = __expf(v[e] - mx); sum += v[e]; }
        #pragma unroll
        for (int e = 0; e < 8; ++e) {
            const float ev = (32 + 8 * j + e < TOK) ? __expf(v[8 + e] - mx) : 0.f;
            v[8 + e] = ev; sum += ev;
        }
        sum += __shfl_xor(sum, 1, 4);
        sum += __shfl_xor(sum, 2, 4);
        const float inv = 1.f / sum;

        uint4 o;
        o.x = f2bf(v[0] * inv)  | ((unsigned)f2bf(v[1] * inv)  << 16);
        o.y = f2bf(v[2] * inv)  | ((unsigned)f2bf(v[3] * inv)  << 16);
        o.z = f2bf(v[4] * inv)  | ((unsigned)f2bf(v[5] * inv)  << 16);
        o.w = f2bf(v[6] * inv)  | ((unsigned)f2bf(v[7] * inv)  << 16);
        *reinterpret_cast<uint4*>(&Ps[swz(n, 8 * j)]) = o;
        o.x = f2bf(v[8] * inv)  | ((unsigned)f2bf(v[9] * inv)  << 16);
        o.y = f2bf(v[10] * inv) | ((unsigned)f2bf(v[11] * inv) << 16);
        o.z = f2bf(v[12] * inv) | ((unsigned)f2bf(v[13] * inv) << 16);
        o.w = f2bf(v[14] * inv) | ((unsigned)f2bf(v[15] * inv) << 16);
        *reinterpret_cast<uint4*>(&Ps[swz(n, 32 + 8 * j)]) = o;
    }
    __syncthreads();

    f32x4 oacc[8];
    #pragma unroll
    for (int nj = 0; nj < 8; ++nj) oacc[nj] = (f32x4)0.0f;
    #pragma unroll
    for (int ks = 0; ks < 2; ++ks) {
        bf16x8 pf = *reinterpret_cast<const bf16x8*>(&Ps[swz(16 * w + fr, ks * 32 + fg * 8)]);
        #pragma unroll
        for (int nj = 0; nj < 8; ++nj) {
            bf16x8 vf = *reinterpret_cast<const bf16x8*>(&Vts[swz(16 * nj + fr, ks * 32 + fg * 8)]);
            oacc[nj] = __builtin_amdgcn_mfma_f32_16x16x32_bf16(pf, vf, oacc[nj], 0, 0, 0);
        }
    }

    // Store O pre-swizzled (T2) for proj-A (validated r10/r11).
    #pragma unroll
    for (int nj = 0; nj < 8; ++nj) {
        const int d = 16 * nj + fr;
        const int c = h * DHEAD + d;
        const int tp = c >> 6, sl = (c >> 3) & 7, cc = c & 7;
        #pragma unroll
        for (int j = 0; j < 4; ++j) {
            const int n = 16 * w + fg * 4 + j;
            if (n < TOK) {
                const int gr = b * TOK + n;
                ab[(size_t)gr * DHTOT + (tp << 6) + (((sl ^ (gr & 7)) << 3) | cc)] = f2bf(oacc[nj][j]);
            }
        }
    }
}

// ---------------------------------------------------------------------------
extern "C" void kernel_launch(void* const* d_in, const int* in_sizes, int n_in,
                              void* d_out, int out_size, void* d_ws, size_t ws_size,
                              hipStream_t stream)
{
    const float* x         = (const float*)d_in[0];
    const float* qkv_w     = (const float*)d_in[1];
    const float* qkv_b     = (const float*)d_in[2];
    const float* proj_w    = (const float*)d_in[3];
    const float* proj_b    = (const float*)d_in[4];
    const float* attn_bias = (const float*)d_in[5];
    const int*   bias_idxs = (const int*)d_in[6];

    const int Mtot  = in_sizes[0] / DIMM;            // 100352
    const int Btot  = Mtot / TOK;                    // 2048
    const int n_off = in_sizes[5] / NH;              // 49

    const size_t nWq = (size_t)HQKV * DIMM;
    const size_t nWp = (size_t)DIMM * DHTOT;
    float* bias_full = (float*)d_ws;                           // 76832 B
    u16*   wq        = (u16*)((char*)d_ws + 76832);
    u16*   wp        = wq + nWq;
    u16*   dyn       = wp + nWp;
    const size_t fixed_bytes = 76832 + (nWq + nWp) * sizeof(u16);
    // per-batch: xb 49*384*2 + qkvb 49*1536*2 + ab 49*1024*2
    const size_t per_batch = (size_t)TOK * (DIMM + HQKV + DHTOT) * 2;

    if (ws_size <= fixed_bytes) return;
    long BcL = (long)((ws_size - fixed_bytes) / per_batch);
    int Bc = (int)((BcL / 128) * 128);       // keep Mc multiple of 128
    if (Bc <= 0) return;
    if (Bc > Btot) Bc = Btot;                // round-3 evidence: single chunk in practice

    cast_swz<<<dim3(288), 256, 0, stream>>>(qkv_w, wq, DIMM / 8, (long)HQKV * (DIMM / 8));
    cast_swz<<<dim3(192), 256, 0, stream>>>(proj_w, wp, DHTOT / 8, (long)DIMM * (DHTOT / 8));
    bias_expand<<<dim3((NH * TOK * TOK + 255) / 256), 256, 0, stream>>>(attn_bias, bias_idxs, bias_full, n_off);

    for (int b0 = 0; b0 < Btot; b0 += Bc) {
        const int bc = (b0 + Bc <= Btot) ? Bc : (Btot - b0);   // multiple of 128
        const int Mc = bc * TOK;

        u16* xb   = dyn;
        u16* qkvb = xb   + (size_t)Bc * TOK * DIMM;
        u16* abb  = qkvb + (size_t)Bc * TOK * HQKV;

        const float* xc   = x + (size_t)b0 * TOK * DIMM;
        float*       outc = (float*)d_out + (size_t)b0 * TOK * DIMM;

        cast_swz<<<dim3(2048), 256, 0, stream>>>(xc, xb, DIMM / 8, (long)Mc * (DIMM / 8));

        gemm_qkv<<<dim3((Mc / 128) * (HQKV / 128)), 256, 0, stream>>>(xb, wq, qkv_b, qkvb, Mc);

        attn_mfma<<<dim3(bc, NH), 256, 0, stream>>>(qkvb, bias_full, abb);

        gemm_bf16_nt<<<dim3((Mc / 128) * (DIMM / 128)), 256, 0, stream>>>(abb, wp, proj_b, outc, Mc, DIMM, DHTOT);
    }
}

// Round 13
// 682.844 us; speedup vs baseline: 3.9607x; 1.0391x over previous
//
#include <hip/hip_runtime.h>
#include <cstddef>
#include <cstdint>

#define TOK    49      // tokens (7x7)
#define KD     32      // key dim
#define NH     8       // heads
#define DHEAD  128     // v head dim
#define HQKV   1536    // qkv channels
#define DHTOT  1024    // NH*DHEAD
#define DIMM   384     // model dim

typedef unsigned short u16;
typedef float  f32x4  __attribute__((ext_vector_type(4)));
typedef __bf16 bf16x8 __attribute__((ext_vector_type(8)));

typedef const __attribute__((address_space(1))) void gas_void;
typedef __attribute__((address_space(3))) void las_void;

static __device__ __forceinline__ u16 f2bf(float f) {
    unsigned int u = __builtin_bit_cast(unsigned int, f);
    return (u16)((u + 0x7fffu + ((u >> 16) & 1u)) >> 16);   // RNE
}

// XOR-swizzled index into a row-major [*][64] bf16 LDS image: 16B slots,
// slot ^= (row&7).  (QKs / Ps — validated r5-r12.)
static __device__ __forceinline__ int swz(int row, int c) {
    return (row << 6) + ((((c >> 3) ^ (row & 7)) << 3) | (c & 7));
}

// Vts swizzle: slot XORs BOTH row&7 and (row>>3)&7. V-scatter writes vary
// only row>>3 across lanes (row&7 fixed) -> old swz was a 16-way write
// conflict (r12: 7.75e7); this spreads writes to 2-way while PV reads
// (row = 16nj+fr, fr varies both fields) stay ~2-way.
static __device__ __forceinline__ int swzV(int row, int c) {
    return (row << 6) + ((((c >> 3) ^ (row & 7) ^ ((row >> 3) & 7)) << 3) | (c & 7));
}

// Bijective XCD-chunked remap (m204).
static __device__ __forceinline__ int xcd_chunk(int bid, int nwg) {
    const int xcd = bid & 7, slot = bid >> 3;
    const int q = nwg >> 3, r = nwg & 7;
    return (xcd < r ? xcd * (q + 1) : r * (q + 1) + (xcd - r) * q) + slot;
}

// T4 primitives: raw barrier + counted vmcnt (never 0 inside K-loop).
#define BAR() __builtin_amdgcn_s_barrier()
#define WAIT_VM8() asm volatile("s_waitcnt vmcnt(8)" ::: "memory")
#define WAIT_VM0() asm volatile("s_waitcnt vmcnt(0)" ::: "memory")

// ---------------------------------------------------------------------------
// fp32 -> bf16 cast with T2 pre-swizzle (validated r10/r11).
// ---------------------------------------------------------------------------
__global__ __launch_bounds__(256)
void cast_swz(const float* __restrict__ in, u16* __restrict__ out, int K8, long nchunk)
{
    long i = (long)blockIdx.x * 256 + threadIdx.x;
    const long stride = (long)gridDim.x * 256;
    for (; i < nchunk; i += stride) {
        const long row = i / K8;
        const int  c8  = (int)(i - row * K8);
        const int  slot = c8 & 7, tpan = c8 >> 3;
        float4 v0 = reinterpret_cast<const float4*>(in)[i * 2];
        float4 v1 = reinterpret_cast<const float4*>(in)[i * 2 + 1];
        uint4 o;
        o.x = f2bf(v0.x) | ((unsigned)f2bf(v0.y) << 16);
        o.y = f2bf(v0.z) | ((unsigned)f2bf(v0.w) << 16);
        o.z = f2bf(v1.x) | ((unsigned)f2bf(v1.y) << 16);
        o.w = f2bf(v1.z) | ((unsigned)f2bf(v1.w) << 16);
        *reinterpret_cast<uint4*>(out + row * (long)K8 * 8 + tpan * 64 +
                                  ((slot ^ ((int)row & 7)) << 3)) = o;
    }
}

// ---------------------------------------------------------------------------
// bias_full[h][n*49+m] = attn_bias[h][bias_idxs[n*49+m]]
// ---------------------------------------------------------------------------
__global__ __launch_bounds__(256)
void bias_expand(const float* __restrict__ attn_bias, const int* __restrict__ idxs,
                 float* __restrict__ bias_full, int n_off)
{
    int i = blockIdx.x * 256 + threadIdx.x;
    if (i < NH * TOK * TOK) {
        int h = i / (TOK * TOK), s = i - h * (TOK * TOK);
        bias_full[i] = attn_bias[h * n_off + idxs[s]];
    }
}

// Fragment read offset in a [rows][64]-short LDS tile with pre-swizzled
// content (validated r10).
static __device__ __forceinline__ int frag_off(int row, int ks8fg) {
    return (row << 6) + (((ks8fg ^ (row & 7)) << 3));
}

// ---------------------------------------------------------------------------
// QKV GEMM: [M,384] @ [1536,384]^T + bias -> plain row-major bf16 [M][1536].
// T4 K-loop: 2-deep prefetch, counted vmcnt(8), raw barriers (validated r12).
// ---------------------------------------------------------------------------
__global__ __launch_bounds__(256)
void gemm_qkv(const u16* __restrict__ A,      // [M][384] bf16 pre-swz
              const u16* __restrict__ W,      // [1536][384] bf16 pre-swz
              const float* __restrict__ bias, // [1536]
              u16* __restrict__ qkvb, int M)
{
    const int K = DIMM;                        // 384 -> 6 K-steps
    const int NB = HQKV / 128;                 // 12
    const int nwg = (M / 128) * NB;
    const int wgid = xcd_chunk(blockIdx.x, nwg);
    const int bm = (wgid / NB) * 128;
    const int bn = (wgid % NB) * 128;

    __shared__ u16 Alds[2][128 * 64];
    __shared__ u16 Blds[2][128 * 64];

    const int t    = threadIdx.x;
    const int lane = t & 63;
    const int wv   = t >> 6;
    const int wr   = wv >> 1;
    const int wc   = wv & 1;

    const int lrow = lane >> 3;
    const int lcol = (lane & 7) * 8;
    const int frow = lane & 15;
    const int fg   = lane >> 4;                // 0..3

    f32x4 acc[4][4];
    #pragma unroll
    for (int mi = 0; mi < 4; ++mi)
        #pragma unroll
        for (int ni = 0; ni < 4; ++ni) acc[mi][ni] = (f32x4)0.0f;

    auto STAGE = [&](int buf, int k0) {
        #pragma unroll
        for (int i = 0; i < 4; ++i) {
            const int c   = i * 4 + wv;
            const int row = c * 8 + lrow;
            __builtin_amdgcn_global_load_lds((gas_void*)(A + (size_t)(bm + row) * K + k0 + lcol),
                                             (las_void*)(&Alds[buf][c * 512]), 16, 0, 0);
            __builtin_amdgcn_global_load_lds((gas_void*)(W + (size_t)(bn + row) * K + k0 + lcol),
                                             (las_void*)(&Blds[buf][c * 512]), 16, 0, 0);
        }
    };

    STAGE(0, 0);
    STAGE(1, 64);

    const int NT = 6;
    for (int ts = 0; ts < NT; ++ts) {
        if (ts < NT - 1) { WAIT_VM8(); }
        else             { WAIT_VM0(); }
        BAR();
        const u16* Ab = Alds[ts & 1];
        const u16* Bb = Blds[ts & 1];
        #pragma unroll
        for (int ks = 0; ks < 2; ++ks) {
            const int sl = ks * 4 + fg;
            bf16x8 af[4], bf[4];
            #pragma unroll
            for (int mi = 0; mi < 4; ++mi)
                af[mi] = *reinterpret_cast<const bf16x8*>(&Ab[frag_off(wr * 64 + mi * 16 + frow, sl)]);
            #pragma unroll
            for (int ni = 0; ni < 4; ++ni)
                bf[ni] = *reinterpret_cast<const bf16x8*>(&Bb[frag_off(wc * 64 + ni * 16 + frow, sl)]);
            #pragma unroll
            for (int mi = 0; mi < 4; ++mi)
                #pragma unroll
                for (int ni = 0; ni < 4; ++ni)
                    acc[mi][ni] = __builtin_amdgcn_mfma_f32_16x16x32_bf16(af[mi], bf[ni], acc[mi][ni], 0, 0, 0);
        }
        BAR();
        if (ts < NT - 2) STAGE(ts & 1, (ts + 2) * 64);
    }

    const int rbase = (lane >> 4) * 4;
    #pragma unroll
    for (int ni = 0; ni < 4; ++ni) {
        const int col = bn + wc * 64 + ni * 16 + frow;
        const float bv = bias[col];
        #pragma unroll
        for (int mi = 0; mi < 4; ++mi) {
            #pragma unroll
            for (int j = 0; j < 4; ++j) {
                const int row = bm + wr * 64 + mi * 16 + rbase + j;
                qkvb[(size_t)row * HQKV + col] = f2bf(acc[mi][ni][j] + bv);
            }
        }
    }
}

// ---------------------------------------------------------------------------
// Proj GEMM: C[M,384] = A[M,1024] @ W[384,1024]^T + bias. Same T4 K-loop.
// ---------------------------------------------------------------------------
__global__ __launch_bounds__(256)
void gemm_bf16_nt(const u16* __restrict__ A, const u16* __restrict__ W,
                  const float* __restrict__ bias, float* __restrict__ C,
                  int M, int N, int K)
{
    const int NB = N / 128;
    const int nwg = (M / 128) * NB;
    const int wgid = xcd_chunk(blockIdx.x, nwg);
    const int bm = (wgid / NB) * 128;
    const int bn = (wgid % NB) * 128;

    __shared__ u16 Alds[2][128 * 64];
    __shared__ u16 Blds[2][128 * 64];

    const int t    = threadIdx.x;
    const int lane = t & 63;
    const int wv   = t >> 6;
    const int wr   = wv >> 1;
    const int wc   = wv & 1;

    const int lrow = lane >> 3;
    const int lcol = (lane & 7) * 8;
    const int frow = lane & 15;
    const int fg   = lane >> 4;

    f32x4 acc[4][4];
    #pragma unroll
    for (int mi = 0; mi < 4; ++mi)
        #pragma unroll
        for (int ni = 0; ni < 4; ++ni) acc[mi][ni] = (f32x4)0.0f;

    auto STAGE = [&](int buf, int k0) {
        #pragma unroll
        for (int i = 0; i < 4; ++i) {
            const int c   = i * 4 + wv;
            const int row = c * 8 + lrow;
            __builtin_amdgcn_global_load_lds((gas_void*)(A + (size_t)(bm + row) * K + k0 + lcol),
                                             (las_void*)(&Alds[buf][c * 512]), 16, 0, 0);
            __builtin_amdgcn_global_load_lds((gas_void*)(W + (size_t)(bn + row) * K + k0 + lcol),
                                             (las_void*)(&Blds[buf][c * 512]), 16, 0, 0);
        }
    };

    const int NT = K / 64;
    STAGE(0, 0);
    STAGE(1, 64);

    for (int ts = 0; ts < NT; ++ts) {
        if (ts < NT - 1) { WAIT_VM8(); }
        else             { WAIT_VM0(); }
        BAR();
        const u16* Ab = Alds[ts & 1];
        const u16* Bb = Blds[ts & 1];
        #pragma unroll
        for (int ks = 0; ks < 2; ++ks) {
            const int sl = ks * 4 + fg;
            bf16x8 af[4], bf[4];
            #pragma unroll
            for (int mi = 0; mi < 4; ++mi)
                af[mi] = *reinterpret_cast<const bf16x8*>(&Ab[frag_off(wr * 64 + mi * 16 + frow, sl)]);
            #pragma unroll
            for (int ni = 0; ni < 4; ++ni)
                bf[ni] = *reinterpret_cast<const bf16x8*>(&Bb[frag_off(wc * 64 + ni * 16 + frow, sl)]);
            #pragma unroll
            for (int mi = 0; mi < 4; ++mi)
                #pragma unroll
                for (int ni = 0; ni < 4; ++ni)
                    acc[mi][ni] = __builtin_amdgcn_mfma_f32_16x16x32_bf16(af[mi], bf[ni], acc[mi][ni], 0, 0, 0);
        }
        BAR();
        if (ts < NT - 2) STAGE(ts & 1, (ts + 2) * 64);
    }

    const int rbase = (lane >> 4) * 4;
    #pragma unroll
    for (int ni = 0; ni < 4; ++ni) {
        const int col = bn + wc * 64 + ni * 16 + frow;
        const float bv = bias[col];
        #pragma unroll
        for (int mi = 0; mi < 4; ++mi) {
            #pragma unroll
            for (int j = 0; j < 4; ++j) {
                const int row = bm + wr * 64 + mi * 16 + rbase + j;
                C[(size_t)row * N + col] = acc[mi][ni][j] + bv;
            }
        }
    }
}

// ---------------------------------------------------------------------------
// MFMA attention (r11 structure). Only change vs r12: Vts uses swzV at all
// 3 sites (pad, scatter-write, PV-read) -> V writes 16-way -> 2-way.
// ---------------------------------------------------------------------------
__global__ __launch_bounds__(256)
void attn_mfma(const u16* __restrict__ qkvb,          // [Mc][1536] bf16
               const float* __restrict__ bias_full,   // [NH][49*49]
               u16* __restrict__ ab)                  // [Mc][1024] pre-swz
{
    __shared__ __align__(16) u16  QKs[64 * 64];
    __shared__ __align__(16) u16  Vts[128 * 64];
    __shared__ __align__(16) float S[64 * 80];
    __shared__ __align__(16) u16  Ps[64 * 64];

    const int t    = threadIdx.x;
    const int lane = t & 63;
    const int w    = t >> 6;
    const int fr   = lane & 15;
    const int fg   = lane >> 4;
    const int b    = blockIdx.x;
    const int h    = blockIdx.y;

    // ---- phase 0: zero V pad (cols 48..63 = orig slots 6,7 of every row) ----
    if (t < 128 * 2) {
        const int row = t >> 1, sl = 6 + (t & 1);
        *reinterpret_cast<uint4*>(&Vts[(row << 6) +
            (((sl ^ (row & 7) ^ ((row >> 3) & 7)) & 7) << 3)]) = make_uint4(0, 0, 0, 0);
    }
    __syncthreads();

    // ---- phase 1: gather (b,h) slice, write LDS ----
    const u16* qrow = qkvb + (size_t)b * TOK * HQKV + h * 192;
    for (int flat = t; flat < TOK * 24; flat += 256) {
        const int n = flat / 24, c24 = flat - n * 24;
        uint4 u = *reinterpret_cast<const uint4*>(qrow + (size_t)n * HQKV + c24 * 8);
        if (c24 < 8) {
            *reinterpret_cast<uint4*>(&QKs[(n << 6) + ((c24 ^ (n & 7)) << 3)]) = u;
        } else {
            const int d0 = (c24 - 8) * 8;
            u16 vals[8];
            *reinterpret_cast<uint4*>(vals) = u;
            #pragma unroll
            for (int e = 0; e < 8; ++e)
                Vts[swzV(d0 + e, n)] = vals[e];
        }
    }
    __syncthreads();

    bf16x8 qf = *reinterpret_cast<const bf16x8*>(&QKs[swz(16 * w + fr, fg * 8)]);
    f32x4 sacc[4];
    #pragma unroll
    for (int nj = 0; nj < 4; ++nj) {
        bf16x8 kf = *reinterpret_cast<const bf16x8*>(&QKs[swz(16 * nj + fr, 32 + fg * 8)]);
        sacc[nj] = __builtin_amdgcn_mfma_f32_16x16x32_bf16(qf, kf, (f32x4)0.0f, 0, 0, 0);
    }

    const float scale = 0.17677669529663687f;  // 32^-0.5
    const float* bh_bias = bias_full + h * (TOK * TOK);
    #pragma unroll
    for (int nj = 0; nj < 4; ++nj) {
        #pragma unroll
        for (int j = 0; j < 4; ++j) {
            const int row = 16 * w + fg * 4 + j;
            const int col = 16 * nj + fr;
            const int rn = row < TOK ? row : TOK - 1;
            const int cm = col < TOK ? col : TOK - 1;
            S[row * 80 + col] = sacc[nj][j] * scale + bh_bias[rn * TOK + cm];
        }
    }
    __syncthreads();

    {
        const int n = t >> 2, j = t & 3;
        const float* Sr = &S[n * 80];
        float v[16];
        #pragma unroll
        for (int e = 0; e < 8; ++e) v[e]     = Sr[8 * j + e];
        #pragma unroll
        for (int e = 0; e < 8; ++e) v[8 + e] = Sr[32 + 8 * j + e];

        float mx = -1e30f;
        #pragma unroll
        for (int e = 0; e < 8; ++e) mx = fmaxf(mx, v[e]);
        #pragma unroll
        for (int e = 0; e < 8; ++e)
            if (32 + 8 * j + e < TOK) mx = fmaxf(mx, v[8 + e]);
        mx = fmaxf(mx, __shfl_xor(mx, 1, 4));
        mx = fmaxf(mx, __shfl_xor(mx, 2, 4));

        float sum = 0.f;
        #pragma unroll
        for (int e = 0; e < 8; ++e) { v[e] = __expf(v[e] - mx); sum += v[e]; }
        #pragma unroll
        for (int e = 0; e < 8; ++e) {
            const float ev = (32 + 8 * j + e < TOK) ? __expf(v[8 + e] - mx) : 0.f;
            v[8 + e] = ev; sum += ev;
        }
        sum += __shfl_xor(sum, 1, 4);
        sum += __shfl_xor(sum, 2, 4);
        const float inv = 1.f / sum;

        uint4 o;
        o.x = f2bf(v[0] * inv)  | ((unsigned)f2bf(v[1] * inv)  << 16);
        o.y = f2bf(v[2] * inv)  | ((unsigned)f2bf(v[3] * inv)  << 16);
        o.z = f2bf(v[4] * inv)  | ((unsigned)f2bf(v[5] * inv)  << 16);
        o.w = f2bf(v[6] * inv)  | ((unsigned)f2bf(v[7] * inv)  << 16);
        *reinterpret_cast<uint4*>(&Ps[swz(n, 8 * j)]) = o;
        o.x = f2bf(v[8] * inv)  | ((unsigned)f2bf(v[9] * inv)  << 16);
        o.y = f2bf(v[10] * inv) | ((unsigned)f2bf(v[11] * inv) << 16);
        o.z = f2bf(v[12] * inv) | ((unsigned)f2bf(v[13] * inv) << 16);
        o.w = f2bf(v[14] * inv) | ((unsigned)f2bf(v[15] * inv) << 16);
        *reinterpret_cast<uint4*>(&Ps[swz(n, 32 + 8 * j)]) = o;
    }
    __syncthreads();

    f32x4 oacc[8];
    #pragma unroll
    for (int nj = 0; nj < 8; ++nj) oacc[nj] = (f32x4)0.0f;
    #pragma unroll
    for (int ks = 0; ks < 2; ++ks) {
        bf16x8 pf = *reinterpret_cast<const bf16x8*>(&Ps[swz(16 * w + fr, ks * 32 + fg * 8)]);
        #pragma unroll
        for (int nj = 0; nj < 8; ++nj) {
            bf16x8 vf = *reinterpret_cast<const bf16x8*>(&Vts[swzV(16 * nj + fr, ks * 32 + fg * 8)]);
            oacc[nj] = __builtin_amdgcn_mfma_f32_16x16x32_bf16(pf, vf, oacc[nj], 0, 0, 0);
        }
    }

    // Store O pre-swizzled (T2) for proj-A (validated r10/r11).
    #pragma unroll
    for (int nj = 0; nj < 8; ++nj) {
        const int d = 16 * nj + fr;
        const int c = h * DHEAD + d;
        const int tp = c >> 6, sl = (c >> 3) & 7, cc = c & 7;
        #pragma unroll
        for (int j = 0; j < 4; ++j) {
            const int n = 16 * w + fg * 4 + j;
            if (n < TOK) {
                const int gr = b * TOK + n;
                ab[(size_t)gr * DHTOT + (tp << 6) + (((sl ^ (gr & 7)) << 3) | cc)] = f2bf(oacc[nj][j]);
            }
        }
    }
}

// ---------------------------------------------------------------------------
extern "C" void kernel_launch(void* const* d_in, const int* in_sizes, int n_in,
                              void* d_out, int out_size, void* d_ws, size_t ws_size,
                              hipStream_t stream)
{
    const float* x         = (const float*)d_in[0];
    const float* qkv_w     = (const float*)d_in[1];
    const float* qkv_b     = (const float*)d_in[2];
    const float* proj_w    = (const float*)d_in[3];
    const float* proj_b    = (const float*)d_in[4];
    const float* attn_bias = (const float*)d_in[5];
    const int*   bias_idxs = (const int*)d_in[6];

    const int Mtot  = in_sizes[0] / DIMM;            // 100352
    const int Btot  = Mtot / TOK;                    // 2048
    const int n_off = in_sizes[5] / NH;              // 49

    const size_t nWq = (size_t)HQKV * DIMM;
    const size_t nWp = (size_t)DIMM * DHTOT;
    float* bias_full = (float*)d_ws;                           // 76832 B
    u16*   wq        = (u16*)((char*)d_ws + 76832);
    u16*   wp        = wq + nWq;
    u16*   dyn       = wp + nWp;
    const size_t fixed_bytes = 76832 + (nWq + nWp) * sizeof(u16);
    // per-batch: xb 49*384*2 + qkvb 49*1536*2 + ab 49*1024*2
    const size_t per_batch = (size_t)TOK * (DIMM + HQKV + DHTOT) * 2;

    if (ws_size <= fixed_bytes) return;
    long BcL = (long)((ws_size - fixed_bytes) / per_batch);
    int Bc = (int)((BcL / 128) * 128);       // keep Mc multiple of 128
    if (Bc <= 0) return;
    if (Bc > Btot) Bc = Btot;                // round-3 evidence: single chunk in practice

    cast_swz<<<dim3(288), 256, 0, stream>>>(qkv_w, wq, DIMM / 8, (long)HQKV * (DIMM / 8));
    cast_swz<<<dim3(192), 256, 0, stream>>>(proj_w, wp, DHTOT / 8, (long)DIMM * (DHTOT / 8));
    bias_expand<<<dim3((NH * TOK * TOK + 255) / 256), 256, 0, stream>>>(attn_bias, bias_idxs, bias_full, n_off);

    for (int b0 = 0; b0 < Btot; b0 += Bc) {
        const int bc = (b0 + Bc <= Btot) ? Bc : (Btot - b0);   // multiple of 128
        const int Mc = bc * TOK;

        u16* xb   = dyn;
        u16* qkvb = xb   + (size_t)Bc * TOK * DIMM;
        u16* abb  = qkvb + (size_t)Bc * TOK * HQKV;

        const float* xc   = x + (size_t)b0 * TOK * DIMM;
        float*       outc = (float*)d_out + (size_t)b0 * TOK * DIMM;

        cast_swz<<<dim3(2048), 256, 0, stream>>>(xc, xb, DIMM / 8, (long)Mc * (DIMM / 8));

        gemm_qkv<<<dim3((Mc / 128) * (HQKV / 128)), 256, 0, stream>>>(xb, wq, qkv_b, qkvb, Mc);

        attn_mfma<<<dim3(bc, NH), 256, 0, stream>>>(qkvb, bias_full, abb);

        gemm_bf16_nt<<<dim3((Mc / 128) * (DIMM / 128)), 256, 0, stream>>>(abb, wp, proj_b, outc, Mc, DIMM, DHTOT);
    }
}